// Round 6
// baseline (669.022 us; speedup 1.0000x reference)
//
#include <hip/hip_runtime.h>
#include <math.h>

#define N_NODES 50000
#define N_EDGES 800000
#define NUM_GRAPHS 256
#define C_IN 64
#define C_H 128
#define D_COUNT 9
#define LRELU_SLOPE 0.01f
#define TAB_BINS 4096
#define TAB_SCALE 512.0f                   // bins per unit distance (covers d in [0,8])
#define WEDGES 64                          // edges per wave
#define NCHUNK (N_EDGES / WEDGES)          // 12500 wave-chunks
#define SCAN_BLK ((N_NODES + 255) / 256)   // 196

__device__ __forceinline__ float fast_rcp(float x) { return __builtin_amdgcn_rcpf(x); }

// ---------------- CSR build (once; edge structure shared by all 3 layers) ------------------

__global__ void hist_kernel(const int* __restrict__ col, int* __restrict__ counts) {
    const int e = blockIdx.x * 256 + threadIdx.x;
    if (e < N_EDGES) atomicAdd(&counts[col[e]], 1);
}

__global__ void scan_a(const int* __restrict__ counts, int* __restrict__ curp,
                       int* __restrict__ blocksums) {
    __shared__ int s[256];
    const int t = threadIdx.x;
    const int i = blockIdx.x * 256 + t;
    const int v = (i < N_NODES) ? counts[i] : 0;
    s[t] = v;
    __syncthreads();
    for (int d = 1; d < 256; d <<= 1) {
        const int x = (t >= d) ? s[t - d] : 0;
        __syncthreads();
        s[t] += x;
        __syncthreads();
    }
    if (i < N_NODES) curp[i] = s[t] - v;
    if (t == 255) blocksums[blockIdx.x] = s[255];
}

__global__ void scan_b(int* __restrict__ blocksums) {
    __shared__ int s[256];
    const int t = threadIdx.x;
    const int v = (t < SCAN_BLK) ? blocksums[t] : 0;
    s[t] = v;
    __syncthreads();
    for (int d = 1; d < 256; d <<= 1) {
        const int x = (t >= d) ? s[t - d] : 0;
        __syncthreads();
        s[t] += x;
        __syncthreads();
    }
    if (t < SCAN_BLK) blocksums[t] = s[t] - v;
}

__global__ void scan_c(int* __restrict__ curp, const int* __restrict__ blocksums) {
    const int i = blockIdx.x * 256 + threadIdx.x;
    if (i < N_NODES) curp[i] += blocksums[blockIdx.x];
}

__global__ void scatter_kernel(const int* __restrict__ row, const int* __restrict__ col,
                               int* __restrict__ cur, int2* __restrict__ rc_csr) {
    const int e = blockIdx.x * 256 + threadIdx.x;
    if (e < N_EDGES) {
        const int cl = col[e];
        const int p = atomicAdd(&cur[cl], 1);
        rc_csr[p] = make_int2(row[e], cl);
    }
}

// ---------------- per-layer radial lookup table --------------------------------------------
// tab[bin][lane] = float4(v0(2l), v0(2l+1), v1(2l)-v0(2l), v1(2l+1)-v0(2l+1))
// where v0 = radial at d = bin/512, v1 at (bin+1)/512. Linear interp -> err ~5e-6.
__global__ void build_table_kernel(const float* __restrict__ Wc, const float* __restrict__ bc,
                                   float4* __restrict__ tab) {
    const int idx = blockIdx.x * 256 + threadIdx.x;
    const int lane = idx & 63;
    const int bin = idx >> 6;
    if (bin >= TAB_BINS) return;
    float v[2][2];
#pragma unroll
    for (int s = 0; s < 2; ++s) {
        const float d = (float)(bin + s) * (1.0f / TAB_SCALE);
#pragma unroll
        for (int p = 0; p < 2; ++p) {
            const int c = 2 * lane + p;
            float a = bc[c];
#pragma unroll
            for (int k = 0; k < D_COUNT; ++k) {
                const float u = (d - 0.75f * (float)k) * 1.5f;  // mu=0.75k, 1/sigma=1.5
                a = fmaf(__expf(-u * u), Wc[k * C_H + c], a);
            }
            v[s][p] = a * fast_rcp(1.0f + __expf(-a));
        }
    }
    tab[idx] = make_float4(v[0][0], v[0][1], v[1][0] - v[0][0], v[1][1] - v[0][1]);
}

// ---------------- h = silu(x @ W_lin + b_lin) ----------------------------------------------
__global__ void lin0_kernel(const float* __restrict__ x, const float* __restrict__ W,
                            const float* __restrict__ b, float* __restrict__ h) {
    __shared__ float xs[8][C_IN];
    const int node0 = blockIdx.x * 8;
    const int t = threadIdx.x;
    for (int i = t; i < 8 * C_IN; i += 128)
        xs[i >> 6][i & 63] = x[node0 * C_IN + i];
    __syncthreads();
    float acc[8];
    const float bcv = b[t];
#pragma unroll
    for (int n = 0; n < 8; ++n) acc[n] = bcv;
    for (int k = 0; k < C_IN; ++k) {
        const float w = W[k * C_H + t];
#pragma unroll
        for (int n = 0; n < 8; ++n) acc[n] = fmaf(xs[n][k], w, acc[n]);
    }
#pragma unroll
    for (int n = 0; n < 8; ++n) {
        const float a = acc[n];
        h[(node0 + n) * C_H + t] = a * fast_rcp(1.0f + __expf(-a));
    }
}

// ---------------- edge-parallel gather-aggregate (table-based radial) ----------------------
// 256 threads = 4 independent waves; each wave owns 64 contiguous CSR edges.
// Phase A: lane=edge -> d, bin, frac -> LDS meta (int4). Phase B: lane=channel pair;
// groups of 8 edges, depth-2 pipelined loads (h-row float2 + table-row float4);
// radial = v + frac*dv (2 FMA); run-accumulate; interior segs plain store, bounds atomic.
__global__ __launch_bounds__(256, 4) void aggregate_kernel(
        const float2* __restrict__ h2, const float* __restrict__ pos,
        const int2* __restrict__ rc_csr, const float4* __restrict__ tab,
        float* __restrict__ agg) {
    __shared__ int4 meta[4][WEDGES];
    const int t = threadIdx.x;
    const int lane = t & 63;
    const int wv = t >> 6;
    const int base = (blockIdx.x * 4 + wv) * WEDGES;

    // Phase A: one edge per lane
    {
        const int2 rc = rc_csr[base + lane];
        const float dx = pos[rc.x * 3 + 0] - pos[rc.y * 3 + 0];
        const float dy = pos[rc.x * 3 + 1] - pos[rc.y * 3 + 1];
        const float dz = pos[rc.x * 3 + 2] - pos[rc.y * 3 + 2];
        const float d = sqrtf(dx * dx + dy * dy + dz * dz);
        const float f = d * TAB_SCALE;
        int bin = (int)f;
        bin = bin < TAB_BINS - 1 ? bin : TAB_BINS - 1;
        float frac = f - (float)bin;
        frac = frac < 1.0f ? frac : 1.0f;
        meta[wv][lane] = make_int4(bin, rc.x, rc.y, __float_as_int(frac));
    }
    asm volatile("s_waitcnt lgkmcnt(0)" ::: "memory");
    __builtin_amdgcn_sched_barrier(0);
    __builtin_amdgcn_wave_barrier();

    float2 hvA[8]; float4 rvA[8]; int colA[8]; float frA[8];
    float2 hvB[8]; float4 rvB[8]; int colB[8]; float frB[8];
    float2 acc = make_float2(0.0f, 0.0f);
    int sCur;
    bool first = true;

#define LOADG(g, HV, RV, CL, FR)                                              \
    {                                                                         \
        _Pragma("unroll")                                                     \
        for (int u = 0; u < 8; ++u) {                                         \
            const int4 m = meta[wv][(g) * 8 + u];                             \
            const int sBin = __builtin_amdgcn_readfirstlane(m.x);             \
            const int sRow = __builtin_amdgcn_readfirstlane(m.y);             \
            CL[u] = __builtin_amdgcn_readfirstlane(m.z);                      \
            FR[u] = __int_as_float(__builtin_amdgcn_readfirstlane(m.w));      \
            HV[u] = h2[(size_t)sRow * 64 + lane];                             \
            RV[u] = tab[(size_t)sBin * 64 + lane];                            \
        }                                                                     \
    }

#define COMPUTEG(HV, RV, CL, FR)                                              \
    {                                                                         \
        _Pragma("unroll")                                                     \
        for (int u = 0; u < 8; ++u) {                                         \
            if (CL[u] != sCur) {                                              \
                float* dst = &agg[(size_t)sCur * C_H + 2 * lane];             \
                if (first) {                                                  \
                    atomicAdd(dst, acc.x); atomicAdd(dst + 1, acc.y);         \
                    first = false;                                            \
                } else {                                                      \
                    dst[0] = acc.x; dst[1] = acc.y;                           \
                }                                                             \
                acc.x = 0.0f; acc.y = 0.0f;                                   \
                sCur = CL[u];                                                 \
            }                                                                 \
            const float rx = fmaf(FR[u], RV[u].z, RV[u].x);                   \
            const float ry = fmaf(FR[u], RV[u].w, RV[u].y);                   \
            acc.x = fmaf(HV[u].x, rx, acc.x);                                 \
            acc.y = fmaf(HV[u].y, ry, acc.y);                                 \
        }                                                                     \
    }

    LOADG(0, hvA, rvA, colA, frA);
    sCur = colA[0];
    LOADG(1, hvB, rvB, colB, frB);
    COMPUTEG(hvA, rvA, colA, frA);
    LOADG(2, hvA, rvA, colA, frA);
    COMPUTEG(hvB, rvB, colB, frB);
    LOADG(3, hvB, rvB, colB, frB);
    COMPUTEG(hvA, rvA, colA, frA);
    LOADG(4, hvA, rvA, colA, frA);
    COMPUTEG(hvB, rvB, colB, frB);
    LOADG(5, hvB, rvB, colB, frB);
    COMPUTEG(hvA, rvA, colA, frA);
    LOADG(6, hvA, rvA, colA, frA);
    COMPUTEG(hvB, rvB, colB, frB);
    LOADG(7, hvB, rvB, colB, frB);
    COMPUTEG(hvA, rvA, colA, frA);
    COMPUTEG(hvB, rvB, colB, frB);

    {
        float* dst = &agg[(size_t)sCur * C_H + 2 * lane];
        atomicAdd(dst, acc.x);
        atomicAdd(dst + 1, acc.y);
    }
#undef LOADG
#undef COMPUTEG
}

// ---------------- h = g * lrelu((h+agg) @ Wn + bn)/sqrt(1+eps) + be  (in place) -------------
__global__ __launch_bounds__(256) void node_kernel(
        float* __restrict__ h, const float* __restrict__ agg,
        const float* __restrict__ Wn, const float* __restrict__ bn,
        const float* __restrict__ g, const float* __restrict__ be) {
    __shared__ float s[32][C_H];
    const int node0 = blockIdx.x * 32;
    const int t = threadIdx.x;
    for (int i = t * 4; i < 32 * C_H; i += 256 * 4) {
        const int n = i >> 7;
        const int c = i & 127;
        if (node0 + n < N_NODES) {
            const float4 hv = *(const float4*)&h[(size_t)(node0 + n) * C_H + c];
            const float4 av = *(const float4*)&agg[(size_t)(node0 + n) * C_H + c];
            float4 r;
            r.x = hv.x + av.x; r.y = hv.y + av.y; r.z = hv.z + av.z; r.w = hv.w + av.w;
            *(float4*)&s[n][c] = r;
        }
    }
    __syncthreads();
    const int wv = t >> 6;
    const int lane = t & 63;
    const int nb = wv * 8;
    const float2 bn2 = *(const float2*)&bn[2 * lane];
    float2 acc[8];
#pragma unroll
    for (int n = 0; n < 8; ++n) acc[n] = bn2;
    for (int k = 0; k < C_H; k += 4) {
        const float2 w0 = *(const float2*)&Wn[(size_t)(k + 0) * C_H + 2 * lane];
        const float2 w1 = *(const float2*)&Wn[(size_t)(k + 1) * C_H + 2 * lane];
        const float2 w2 = *(const float2*)&Wn[(size_t)(k + 2) * C_H + 2 * lane];
        const float2 w3 = *(const float2*)&Wn[(size_t)(k + 3) * C_H + 2 * lane];
#pragma unroll
        for (int n = 0; n < 8; ++n) {
            const float4 sv = *(const float4*)&s[nb + n][k];
            acc[n].x = fmaf(sv.x, w0.x, acc[n].x); acc[n].y = fmaf(sv.x, w0.y, acc[n].y);
            acc[n].x = fmaf(sv.y, w1.x, acc[n].x); acc[n].y = fmaf(sv.y, w1.y, acc[n].y);
            acc[n].x = fmaf(sv.z, w2.x, acc[n].x); acc[n].y = fmaf(sv.z, w2.y, acc[n].y);
            acc[n].x = fmaf(sv.w, w3.x, acc[n].x); acc[n].y = fmaf(sv.w, w3.y, acc[n].y);
        }
    }
    const float inv = 0.9999950000374997f;  // 1/sqrt(1+1e-5)
    float2 g2 = *(const float2*)&g[2 * lane];
    g2.x *= inv; g2.y *= inv;
    const float2 be2 = *(const float2*)&be[2 * lane];
#pragma unroll
    for (int n = 0; n < 8; ++n) {
        const int node = node0 + nb + n;
        if (node < N_NODES) {
            float2 v = acc[n];
            v.x = v.x > 0.0f ? v.x : LRELU_SLOPE * v.x;
            v.y = v.y > 0.0f ? v.y : LRELU_SLOPE * v.y;
            float2 o;
            o.x = fmaf(g2.x, v.x, be2.x);
            o.y = fmaf(g2.y, v.y, be2.y);
            *(float2*)&h[(size_t)node * C_H + 2 * lane] = o;
        }
    }
}

// ---------------- global_add_pool (batch sorted -> run-accumulate) ---------------------------
__global__ void pool_kernel(const float* __restrict__ h, const int* __restrict__ batch,
                            float* __restrict__ out) {
    const int CHUNK = 250;
    const int n0 = blockIdx.x * CHUNK;
    int n1 = n0 + CHUNK;
    if (n1 > N_NODES) n1 = N_NODES;
    const int c = threadIdx.x;
    float acc = 0.0f;
    int curb = batch[n0];
    for (int n = n0; n < n1; ++n) {
        const int bb = batch[n];
        if (bb != curb) {
            atomicAdd(&out[curb * C_H + c], acc);
            acc = 0.0f;
            curb = bb;
        }
        acc += h[n * C_H + c];
    }
    atomicAdd(&out[curb * C_H + c], acc);
}

extern "C" void kernel_launch(void* const* d_in, const int* in_sizes, int n_in,
                              void* d_out, int out_size, void* d_ws, size_t ws_size,
                              hipStream_t stream) {
    const float* x     = (const float*)d_in[0];
    const float* pos   = (const float*)d_in[1];
    const int*   eidx  = (const int*)d_in[2];
    const int*   batch = (const int*)d_in[3];
    const float* W_lin = (const float*)d_in[4];
    const float* b_lin = (const float*)d_in[5];

    float* h   = (float*)d_ws;                            // 6,400,000 f
    float* agg = h + (size_t)N_NODES * C_H;               // 6,400,000 f
    int* counts    = (int*)(agg + (size_t)N_NODES * C_H); // 50,000
    int* curp      = counts + N_NODES;                    // 50,000
    int* blocksums = curp + N_NODES;                      // 256
    int2* rc_csr   = (int2*)(blocksums + 256);            // 800,000 int2
    float4* tab    = (float4*)(rc_csr + N_EDGES);         // 4096*64 float4 = 4 MB

    const int* row = eidx;
    const int* col = eidx + N_EDGES;

    // CSR build
    hipMemsetAsync(counts, 0, N_NODES * sizeof(int), stream);
    hipLaunchKernelGGL(hist_kernel, dim3((N_EDGES + 255) / 256), dim3(256), 0, stream,
                       col, counts);
    hipLaunchKernelGGL(scan_a, dim3(SCAN_BLK), dim3(256), 0, stream,
                       counts, curp, blocksums);
    hipLaunchKernelGGL(scan_b, dim3(1), dim3(256), 0, stream, blocksums);
    hipLaunchKernelGGL(scan_c, dim3(SCAN_BLK), dim3(256), 0, stream, curp, blocksums);
    hipLaunchKernelGGL(scatter_kernel, dim3((N_EDGES + 255) / 256), dim3(256), 0, stream,
                       row, col, curp, rc_csr);

    hipLaunchKernelGGL(lin0_kernel, dim3(N_NODES / 8), dim3(128), 0, stream,
                       x, W_lin, b_lin, h);

    for (int l = 0; l < 3; ++l) {
        const float* Wc = (const float*)d_in[6 + l * 6 + 0];
        const float* bc = (const float*)d_in[6 + l * 6 + 1];
        const float* Wn = (const float*)d_in[6 + l * 6 + 2];
        const float* bn = (const float*)d_in[6 + l * 6 + 3];
        const float* g  = (const float*)d_in[6 + l * 6 + 4];
        const float* be = (const float*)d_in[6 + l * 6 + 5];

        hipLaunchKernelGGL(build_table_kernel, dim3(TAB_BINS * 64 / 256), dim3(256), 0, stream,
                           Wc, bc, tab);
        hipMemsetAsync(agg, 0, (size_t)N_NODES * C_H * sizeof(float), stream);
        hipLaunchKernelGGL(aggregate_kernel, dim3(NCHUNK / 4), dim3(256), 0, stream,
                           (const float2*)h, pos, rc_csr, tab, agg);
        hipLaunchKernelGGL(node_kernel, dim3((N_NODES + 31) / 32), dim3(256), 0, stream,
                           h, agg, Wn, bn, g, be);
    }

    hipMemsetAsync(d_out, 0, (size_t)NUM_GRAPHS * C_H * sizeof(float), stream);
    hipLaunchKernelGGL(pool_kernel, dim3((N_NODES + 249) / 250), dim3(128), 0, stream,
                       h, batch, (float*)d_out);
}

// Round 7
// 479.127 us; speedup vs baseline: 1.3963x; 1.3963x over previous
//
#include <hip/hip_runtime.h>
#include <math.h>

#define N_NODES 50000
#define N_EDGES 800000
#define NUM_GRAPHS 256
#define C_IN 64
#define C_H 128
#define D_COUNT 9
#define LRELU_SLOPE 0.01f
#define WEDGES 64                          // edges per wave
#define NCHUNK (N_EDGES / WEDGES)          // 12500 wave-chunks
#define SCAN_BLK ((N_NODES + 255) / 256)   // 196

__device__ __forceinline__ float fast_rcp(float x) { return __builtin_amdgcn_rcpf(x); }

// pack two floats -> bf16x2 (RNE), lo channel in low 16 bits
__device__ __forceinline__ unsigned int pack_bf2(float fx, float fy) {
    unsigned int a = __float_as_uint(fx);
    unsigned int b = __float_as_uint(fy);
    a += 0x7fffu + ((a >> 16) & 1u);
    b += 0x7fffu + ((b >> 16) & 1u);
    return (a >> 16) | (b & 0xffff0000u);
}
__device__ __forceinline__ float2 unpack_bf2(unsigned int u) {
    float2 r;
    r.x = __uint_as_float(u << 16);
    r.y = __uint_as_float(u & 0xffff0000u);
    return r;
}

// ---------------- CSR build (once; edge structure shared by all 3 layers) ------------------

__global__ void hist_kernel(const int* __restrict__ col, int* __restrict__ counts) {
    const int e = blockIdx.x * 256 + threadIdx.x;
    if (e < N_EDGES) atomicAdd(&counts[col[e]], 1);
}

__global__ void scan_a(const int* __restrict__ counts, int* __restrict__ curp,
                       int* __restrict__ blocksums) {
    __shared__ int s[256];
    const int t = threadIdx.x;
    const int i = blockIdx.x * 256 + t;
    const int v = (i < N_NODES) ? counts[i] : 0;
    s[t] = v;
    __syncthreads();
    for (int d = 1; d < 256; d <<= 1) {
        const int x = (t >= d) ? s[t - d] : 0;
        __syncthreads();
        s[t] += x;
        __syncthreads();
    }
    if (i < N_NODES) curp[i] = s[t] - v;
    if (t == 255) blocksums[blockIdx.x] = s[255];
}

__global__ void scan_b(int* __restrict__ blocksums) {
    __shared__ int s[256];
    const int t = threadIdx.x;
    const int v = (t < SCAN_BLK) ? blocksums[t] : 0;
    s[t] = v;
    __syncthreads();
    for (int d = 1; d < 256; d <<= 1) {
        const int x = (t >= d) ? s[t - d] : 0;
        __syncthreads();
        s[t] += x;
        __syncthreads();
    }
    if (t < SCAN_BLK) blocksums[t] = s[t] - v;
}

__global__ void scan_c(int* __restrict__ curp, const int* __restrict__ blocksums) {
    const int i = blockIdx.x * 256 + threadIdx.x;
    if (i < N_NODES) curp[i] += blocksums[blockIdx.x];
}

__global__ void scatter_kernel(const int* __restrict__ row, const int* __restrict__ col,
                               int* __restrict__ cur, int2* __restrict__ rc_csr) {
    const int e = blockIdx.x * 256 + threadIdx.x;
    if (e < N_EDGES) {
        const int cl = col[e];
        const int p = atomicAdd(&cur[cl], 1);
        rc_csr[p] = make_int2(row[e], cl);
    }
}

// ---------------- hbf = pack_bf16(silu(x @ W_lin + b_lin)) ---------------------------------
// 256 threads = 4 waves, 32 nodes/block; wave -> 8 nodes, lane -> channel pair.
__global__ __launch_bounds__(256) void lin0_kernel(
        const float* __restrict__ x, const float* __restrict__ W,
        const float* __restrict__ b, unsigned int* __restrict__ hbf) {
    __shared__ float xs[32][C_IN];
    const int node0 = blockIdx.x * 32;
    const int t = threadIdx.x;
    for (int i = t * 4; i < 32 * C_IN; i += 256 * 4) {
        const int n = i >> 6;
        const int c = i & 63;
        if (node0 + n < N_NODES)
            *(float4*)&xs[n][c] = *(const float4*)&x[(size_t)(node0 + n) * C_IN + c];
    }
    __syncthreads();
    const int wv = t >> 6;
    const int lane = t & 63;
    const int nb = wv * 8;
    const float2 b2 = *(const float2*)&b[2 * lane];
    float2 acc[8];
#pragma unroll
    for (int n = 0; n < 8; ++n) acc[n] = b2;
    for (int k = 0; k < C_IN; k += 4) {
        const float2 w0 = *(const float2*)&W[(size_t)(k + 0) * C_H + 2 * lane];
        const float2 w1 = *(const float2*)&W[(size_t)(k + 1) * C_H + 2 * lane];
        const float2 w2 = *(const float2*)&W[(size_t)(k + 2) * C_H + 2 * lane];
        const float2 w3 = *(const float2*)&W[(size_t)(k + 3) * C_H + 2 * lane];
#pragma unroll
        for (int n = 0; n < 8; ++n) {
            const float4 sv = *(const float4*)&xs[nb + n][k];
            acc[n].x = fmaf(sv.x, w0.x, acc[n].x); acc[n].y = fmaf(sv.x, w0.y, acc[n].y);
            acc[n].x = fmaf(sv.y, w1.x, acc[n].x); acc[n].y = fmaf(sv.y, w1.y, acc[n].y);
            acc[n].x = fmaf(sv.z, w2.x, acc[n].x); acc[n].y = fmaf(sv.z, w2.y, acc[n].y);
            acc[n].x = fmaf(sv.w, w3.x, acc[n].x); acc[n].y = fmaf(sv.w, w3.y, acc[n].y);
        }
    }
#pragma unroll
    for (int n = 0; n < 8; ++n) {
        const int node = node0 + nb + n;
        if (node < N_NODES) {
            const float ax = acc[n].x, ay = acc[n].y;
            const float sx = ax * fast_rcp(1.0f + __expf(-ax));
            const float sy = ay * fast_rcp(1.0f + __expf(-ay));
            hbf[(size_t)node * 64 + lane] = pack_bf2(sx, sy);
        }
    }
}

// ---------------- edge-parallel gather-aggregate (in-register radial, bf16 h) --------------
// 256 threads = 4 independent waves; wave owns 64 contiguous CSR edges.
// Phase A: lane=edge -> d, 9 RBFs + row/col bits -> LDS [64][12].
// Phase B: lane=channel pair; 8 groups of 8 edges, depth-2 pipelined bf16 h-gather;
// radial = silu(rbf·wc + bc) in fp32; run-accumulate; interior segs plain store,
// chunk-boundary segs atomicAdd.
__global__ __launch_bounds__(256) void aggregate_kernel(
        const unsigned int* __restrict__ hbf, const float* __restrict__ pos,
        const int2* __restrict__ rc_csr,
        const float* __restrict__ Wc, const float* __restrict__ bc,
        float* __restrict__ agg) {
    __shared__ float rbf_s[4][WEDGES][12];   // 12 KB/block
    const int t = threadIdx.x;
    const int lane = t & 63;
    const int wv = t >> 6;
    const int base = (blockIdx.x * 4 + wv) * WEDGES;

    float2 wc2[D_COUNT];
#pragma unroll
    for (int k = 0; k < D_COUNT; ++k)
        wc2[k] = *(const float2*)&Wc[k * C_H + 2 * lane];
    const float2 bc2 = *(const float2*)&bc[2 * lane];

    // Phase A: one edge per lane
    {
        const int2 rc = rc_csr[base + lane];
        const float dx = pos[rc.x * 3 + 0] - pos[rc.y * 3 + 0];
        const float dy = pos[rc.x * 3 + 1] - pos[rc.y * 3 + 1];
        const float dz = pos[rc.x * 3 + 2] - pos[rc.y * 3 + 2];
        const float d = sqrtf(dx * dx + dy * dy + dz * dz);
#pragma unroll
        for (int k = 0; k < D_COUNT; ++k) {
            const float u = fmaf(d, 1.5f, -1.125f * (float)k);  // (d - 0.75k)*1.5
            rbf_s[wv][lane][k] = __expf(-u * u);
        }
        rbf_s[wv][lane][9]  = __int_as_float(rc.x);
        rbf_s[wv][lane][10] = __int_as_float(rc.y);
    }
    asm volatile("s_waitcnt lgkmcnt(0)" ::: "memory");
    __builtin_amdgcn_sched_barrier(0);
    __builtin_amdgcn_wave_barrier();

    unsigned int huA[8], huB[8];
    float r8A[8], r8B[8];
    int colA[8], colB[8];
    float2 acc = make_float2(0.0f, 0.0f);
    int sCur;
    bool first = true;

#define LOADG(g, HU, R8, CO)                                                  \
    {                                                                         \
        _Pragma("unroll")                                                     \
        for (int u = 0; u < 8; ++u) {                                         \
            const float4 m = *(const float4*)&rbf_s[wv][(g) * 8 + u][8];      \
            const int sRow = __builtin_amdgcn_readfirstlane(__float_as_int(m.y)); \
            CO[u] = __builtin_amdgcn_readfirstlane(__float_as_int(m.z));      \
            R8[u] = m.x;                                                      \
            HU[u] = hbf[(size_t)sRow * 64 + lane];                            \
        }                                                                     \
    }

#define COMPUTEG(g, HU, R8, CO)                                               \
    {                                                                         \
        _Pragma("unroll")                                                     \
        for (int u = 0; u < 8; ++u) {                                         \
            if (CO[u] != sCur) {                                              \
                float* dst = &agg[(size_t)sCur * C_H + 2 * lane];             \
                if (first) {                                                  \
                    atomicAdd(dst, acc.x); atomicAdd(dst + 1, acc.y);         \
                    first = false;                                            \
                } else {                                                      \
                    dst[0] = acc.x; dst[1] = acc.y;                           \
                }                                                             \
                acc.x = 0.0f; acc.y = 0.0f;                                   \
                sCur = CO[u];                                                 \
            }                                                                 \
            const float4 r0 = *(const float4*)&rbf_s[wv][(g) * 8 + u][0];     \
            const float4 r1 = *(const float4*)&rbf_s[wv][(g) * 8 + u][4];     \
            float2 a0, a1;                                                    \
            a0.x = fmaf(r0.x, wc2[0].x, bc2.x); a0.y = fmaf(r0.x, wc2[0].y, bc2.y); \
            a1.x = r0.z * wc2[2].x;             a1.y = r0.z * wc2[2].y;       \
            a0.x = fmaf(r0.y, wc2[1].x, a0.x);  a0.y = fmaf(r0.y, wc2[1].y, a0.y); \
            a1.x = fmaf(r0.w, wc2[3].x, a1.x);  a1.y = fmaf(r0.w, wc2[3].y, a1.y); \
            a0.x = fmaf(r1.x, wc2[4].x, a0.x);  a0.y = fmaf(r1.x, wc2[4].y, a0.y); \
            a1.x = fmaf(r1.y, wc2[5].x, a1.x);  a1.y = fmaf(r1.y, wc2[5].y, a1.y); \
            a0.x = fmaf(r1.z, wc2[6].x, a0.x);  a0.y = fmaf(r1.z, wc2[6].y, a0.y); \
            a1.x = fmaf(r1.w, wc2[7].x, a1.x);  a1.y = fmaf(r1.w, wc2[7].y, a1.y); \
            a0.x = fmaf(R8[u], wc2[8].x, a0.x); a0.y = fmaf(R8[u], wc2[8].y, a0.y); \
            const float axv = a0.x + a1.x;                                    \
            const float ayv = a0.y + a1.y;                                    \
            const float sgx = axv * fast_rcp(1.0f + __expf(-axv));            \
            const float sgy = ayv * fast_rcp(1.0f + __expf(-ayv));            \
            const float2 hv = unpack_bf2(HU[u]);                              \
            acc.x = fmaf(hv.x, sgx, acc.x);                                   \
            acc.y = fmaf(hv.y, sgy, acc.y);                                   \
        }                                                                     \
    }

    LOADG(0, huA, r8A, colA);
    sCur = colA[0];
    LOADG(1, huB, r8B, colB);
    COMPUTEG(0, huA, r8A, colA);
    LOADG(2, huA, r8A, colA);
    COMPUTEG(1, huB, r8B, colB);
    LOADG(3, huB, r8B, colB);
    COMPUTEG(2, huA, r8A, colA);
    LOADG(4, huA, r8A, colA);
    COMPUTEG(3, huB, r8B, colB);
    LOADG(5, huB, r8B, colB);
    COMPUTEG(4, huA, r8A, colA);
    LOADG(6, huA, r8A, colA);
    COMPUTEG(5, huB, r8B, colB);
    LOADG(7, huB, r8B, colB);
    COMPUTEG(6, huA, r8A, colA);
    COMPUTEG(7, huB, r8B, colB);

    {
        float* dst = &agg[(size_t)sCur * C_H + 2 * lane];
        atomicAdd(dst, acc.x);
        atomicAdd(dst + 1, acc.y);
    }
#undef LOADG
#undef COMPUTEG
}

// ---------------- hbf = pack(g * lrelu((hbf+agg) @ Wn + bn)/sqrt(1+eps) + be) ---------------
__global__ __launch_bounds__(256) void node_kernel(
        unsigned int* __restrict__ hbf, const float2* __restrict__ agg2,
        const float* __restrict__ Wn, const float* __restrict__ bn,
        const float* __restrict__ g, const float* __restrict__ be) {
    __shared__ float s[32][C_H];
    const int node0 = blockIdx.x * 32;
    const int t = threadIdx.x;
    for (int i = t; i < 32 * 64; i += 256) {
        const int n = i >> 6;
        const int p = i & 63;
        if (node0 + n < N_NODES) {
            const float2 hv = unpack_bf2(hbf[(size_t)(node0 + n) * 64 + p]);
            const float2 av = agg2[(size_t)(node0 + n) * 64 + p];
            float2 r;
            r.x = hv.x + av.x;
            r.y = hv.y + av.y;
            *(float2*)&s[n][2 * p] = r;
        }
    }
    __syncthreads();
    const int wv = t >> 6;
    const int lane = t & 63;
    const int nb = wv * 8;
    const float2 bn2 = *(const float2*)&bn[2 * lane];
    float2 acc[8];
#pragma unroll
    for (int n = 0; n < 8; ++n) acc[n] = bn2;
    for (int k = 0; k < C_H; k += 4) {
        const float2 w0 = *(const float2*)&Wn[(size_t)(k + 0) * C_H + 2 * lane];
        const float2 w1 = *(const float2*)&Wn[(size_t)(k + 1) * C_H + 2 * lane];
        const float2 w2 = *(const float2*)&Wn[(size_t)(k + 2) * C_H + 2 * lane];
        const float2 w3 = *(const float2*)&Wn[(size_t)(k + 3) * C_H + 2 * lane];
#pragma unroll
        for (int n = 0; n < 8; ++n) {
            const float4 sv = *(const float4*)&s[nb + n][k];
            acc[n].x = fmaf(sv.x, w0.x, acc[n].x); acc[n].y = fmaf(sv.x, w0.y, acc[n].y);
            acc[n].x = fmaf(sv.y, w1.x, acc[n].x); acc[n].y = fmaf(sv.y, w1.y, acc[n].y);
            acc[n].x = fmaf(sv.z, w2.x, acc[n].x); acc[n].y = fmaf(sv.z, w2.y, acc[n].y);
            acc[n].x = fmaf(sv.w, w3.x, acc[n].x); acc[n].y = fmaf(sv.w, w3.y, acc[n].y);
        }
    }
    const float inv = 0.9999950000374997f;  // 1/sqrt(1+1e-5)
    float2 g2 = *(const float2*)&g[2 * lane];
    g2.x *= inv; g2.y *= inv;
    const float2 be2 = *(const float2*)&be[2 * lane];
#pragma unroll
    for (int n = 0; n < 8; ++n) {
        const int node = node0 + nb + n;
        if (node < N_NODES) {
            float2 v = acc[n];
            v.x = v.x > 0.0f ? v.x : LRELU_SLOPE * v.x;
            v.y = v.y > 0.0f ? v.y : LRELU_SLOPE * v.y;
            const float ox = fmaf(g2.x, v.x, be2.x);
            const float oy = fmaf(g2.y, v.y, be2.y);
            hbf[(size_t)node * 64 + lane] = pack_bf2(ox, oy);
        }
    }
}

// ---------------- global_add_pool (batch sorted -> run-accumulate) ---------------------------
// 64 threads = 1 wave; lane = channel pair; 125 nodes per block.
__global__ void pool_kernel(const unsigned int* __restrict__ hbf,
                            const int* __restrict__ batch, float* __restrict__ out) {
    const int CHUNK = 125;
    const int n0 = blockIdx.x * CHUNK;
    const int n1 = n0 + CHUNK;
    const int lane = threadIdx.x;
    float2 acc = make_float2(0.0f, 0.0f);
    int curb = batch[n0];
    for (int n = n0; n < n1; ++n) {
        const int bb = batch[n];
        if (bb != curb) {
            atomicAdd(&out[curb * C_H + 2 * lane], acc.x);
            atomicAdd(&out[curb * C_H + 2 * lane + 1], acc.y);
            acc = make_float2(0.0f, 0.0f);
            curb = bb;
        }
        const float2 hv = unpack_bf2(hbf[(size_t)n * 64 + lane]);
        acc.x += hv.x;
        acc.y += hv.y;
    }
    atomicAdd(&out[curb * C_H + 2 * lane], acc.x);
    atomicAdd(&out[curb * C_H + 2 * lane + 1], acc.y);
}

extern "C" void kernel_launch(void* const* d_in, const int* in_sizes, int n_in,
                              void* d_out, int out_size, void* d_ws, size_t ws_size,
                              hipStream_t stream) {
    const float* x     = (const float*)d_in[0];
    const float* pos   = (const float*)d_in[1];
    const int*   eidx  = (const int*)d_in[2];
    const int*   batch = (const int*)d_in[3];
    const float* W_lin = (const float*)d_in[4];
    const float* b_lin = (const float*)d_in[5];

    // workspace: agg 25.6 MB, hbf 12.8 MB, CSR ~7 MB  (total ~45.6 MB)
    float* agg = (float*)d_ws;                                  // 6,400,000 f
    unsigned int* hbf = (unsigned int*)(agg + (size_t)N_NODES * C_H);  // 3,200,000 u32
    int* counts    = (int*)(hbf + (size_t)N_NODES * 64);        // 50,000
    int* curp      = counts + N_NODES;                          // 50,000
    int* blocksums = curp + N_NODES;                            // 256
    int2* rc_csr   = (int2*)(blocksums + 256);                  // 800,000 int2

    const int* row = eidx;
    const int* col = eidx + N_EDGES;

    // CSR build
    hipMemsetAsync(counts, 0, N_NODES * sizeof(int), stream);
    hipLaunchKernelGGL(hist_kernel, dim3((N_EDGES + 255) / 256), dim3(256), 0, stream,
                       col, counts);
    hipLaunchKernelGGL(scan_a, dim3(SCAN_BLK), dim3(256), 0, stream,
                       counts, curp, blocksums);
    hipLaunchKernelGGL(scan_b, dim3(1), dim3(256), 0, stream, blocksums);
    hipLaunchKernelGGL(scan_c, dim3(SCAN_BLK), dim3(256), 0, stream, curp, blocksums);
    hipLaunchKernelGGL(scatter_kernel, dim3((N_EDGES + 255) / 256), dim3(256), 0, stream,
                       row, col, curp, rc_csr);

    hipLaunchKernelGGL(lin0_kernel, dim3((N_NODES + 31) / 32), dim3(256), 0, stream,
                       x, W_lin, b_lin, hbf);

    for (int l = 0; l < 3; ++l) {
        const float* Wc = (const float*)d_in[6 + l * 6 + 0];
        const float* bc = (const float*)d_in[6 + l * 6 + 1];
        const float* Wn = (const float*)d_in[6 + l * 6 + 2];
        const float* bn = (const float*)d_in[6 + l * 6 + 3];
        const float* g  = (const float*)d_in[6 + l * 6 + 4];
        const float* be = (const float*)d_in[6 + l * 6 + 5];

        hipMemsetAsync(agg, 0, (size_t)N_NODES * C_H * sizeof(float), stream);
        hipLaunchKernelGGL(aggregate_kernel, dim3(NCHUNK / 4), dim3(256), 0, stream,
                           hbf, pos, rc_csr, Wc, bc, agg);
        hipLaunchKernelGGL(node_kernel, dim3((N_NODES + 31) / 32), dim3(256), 0, stream,
                           hbf, (const float2*)agg, Wn, bn, g, be);
    }

    hipMemsetAsync(d_out, 0, (size_t)NUM_GRAPHS * C_H * sizeof(float), stream);
    hipLaunchKernelGGL(pool_kernel, dim3(N_NODES / 125), dim3(64), 0, stream,
                       hbf, batch, (float*)d_out);
}

// Round 8
// 416.900 us; speedup vs baseline: 1.6048x; 1.1493x over previous
//
#include <hip/hip_runtime.h>
#include <hip/hip_fp16.h>
#include <math.h>

#define N_NODES 50000
#define N_EDGES 800000
#define NUM_GRAPHS 256
#define C_IN 64
#define C_H 128
#define D_COUNT 9
#define LRELU_SLOPE 0.01f
#define WEDGES 64                          // edges per wave
#define NCHUNK (N_EDGES / WEDGES)          // 12500 wave-chunks
#define SCAN_BLK ((N_NODES + 255) / 256)   // 196

__device__ __forceinline__ float fast_rcp(float x) { return __builtin_amdgcn_rcpf(x); }
__device__ __forceinline__ __half2 u2h2(unsigned int u) { return __builtin_bit_cast(__half2, u); }
__device__ __forceinline__ unsigned int h22u(__half2 h) { return __builtin_bit_cast(unsigned int, h); }

// ---------------- CSR build (once; edge structure shared by all 3 layers) ------------------

__global__ void hist_kernel(const int* __restrict__ col, int* __restrict__ counts) {
    const int e = blockIdx.x * 256 + threadIdx.x;
    if (e < N_EDGES) atomicAdd(&counts[col[e]], 1);
}

__global__ void scan_a(const int* __restrict__ counts, int* __restrict__ curp,
                       int* __restrict__ blocksums) {
    __shared__ int s[256];
    const int t = threadIdx.x;
    const int i = blockIdx.x * 256 + t;
    const int v = (i < N_NODES) ? counts[i] : 0;
    s[t] = v;
    __syncthreads();
    for (int d = 1; d < 256; d <<= 1) {
        const int x = (t >= d) ? s[t - d] : 0;
        __syncthreads();
        s[t] += x;
        __syncthreads();
    }
    if (i < N_NODES) curp[i] = s[t] - v;
    if (t == 255) blocksums[blockIdx.x] = s[255];
}

__global__ void scan_b(int* __restrict__ blocksums) {
    __shared__ int s[256];
    const int t = threadIdx.x;
    const int v = (t < SCAN_BLK) ? blocksums[t] : 0;
    s[t] = v;
    __syncthreads();
    for (int d = 1; d < 256; d <<= 1) {
        const int x = (t >= d) ? s[t - d] : 0;
        __syncthreads();
        s[t] += x;
        __syncthreads();
    }
    if (t < SCAN_BLK) blocksums[t] = s[t] - v;
}

__global__ void scan_c(int* __restrict__ curp, const int* __restrict__ blocksums) {
    const int i = blockIdx.x * 256 + threadIdx.x;
    if (i < N_NODES) curp[i] += blocksums[blockIdx.x];
}

__global__ void scatter_kernel(const int* __restrict__ row, const int* __restrict__ col,
                               int* __restrict__ cur, int2* __restrict__ rc_csr) {
    const int e = blockIdx.x * 256 + threadIdx.x;
    if (e < N_EDGES) {
        const int cl = col[e];
        const int p = atomicAdd(&cur[cl], 1);
        rc_csr[p] = make_int2(row[e], cl);
    }
}

// ---------------- Wn -> half2 pairs: Wnh[k][p] = (Wn[k][2p], Wn[k][2p+1]) ------------------
__global__ void cvt_wn_kernel(const float* __restrict__ Wn, unsigned int* __restrict__ Wnh) {
    const int i = blockIdx.x * 256 + threadIdx.x;
    if (i < C_H * 64) {
        const int k = i >> 6, p = i & 63;
        Wnh[i] = h22u(__floats2half2_rn(Wn[k * C_H + 2 * p], Wn[k * C_H + 2 * p + 1]));
    }
}

// ---------------- hhf = half2(silu(x @ W_lin + b_lin)) -------------------------------------
__global__ __launch_bounds__(256) void lin0_kernel(
        const float* __restrict__ x, const float* __restrict__ W,
        const float* __restrict__ b, unsigned int* __restrict__ hhf) {
    __shared__ float xs[32][C_IN];
    const int node0 = blockIdx.x * 32;
    const int t = threadIdx.x;
    for (int i = t * 4; i < 32 * C_IN; i += 256 * 4) {
        const int n = i >> 6;
        const int c = i & 63;
        if (node0 + n < N_NODES)
            *(float4*)&xs[n][c] = *(const float4*)&x[(size_t)(node0 + n) * C_IN + c];
    }
    __syncthreads();
    const int wv = t >> 6;
    const int lane = t & 63;
    const int nb = wv * 8;
    const float2 b2 = *(const float2*)&b[2 * lane];
    float2 acc[8];
#pragma unroll
    for (int n = 0; n < 8; ++n) acc[n] = b2;
    for (int k = 0; k < C_IN; k += 4) {
        const float2 w0 = *(const float2*)&W[(size_t)(k + 0) * C_H + 2 * lane];
        const float2 w1 = *(const float2*)&W[(size_t)(k + 1) * C_H + 2 * lane];
        const float2 w2 = *(const float2*)&W[(size_t)(k + 2) * C_H + 2 * lane];
        const float2 w3 = *(const float2*)&W[(size_t)(k + 3) * C_H + 2 * lane];
#pragma unroll
        for (int n = 0; n < 8; ++n) {
            const float4 sv = *(const float4*)&xs[nb + n][k];
            acc[n].x = fmaf(sv.x, w0.x, acc[n].x); acc[n].y = fmaf(sv.x, w0.y, acc[n].y);
            acc[n].x = fmaf(sv.y, w1.x, acc[n].x); acc[n].y = fmaf(sv.y, w1.y, acc[n].y);
            acc[n].x = fmaf(sv.z, w2.x, acc[n].x); acc[n].y = fmaf(sv.z, w2.y, acc[n].y);
            acc[n].x = fmaf(sv.w, w3.x, acc[n].x); acc[n].y = fmaf(sv.w, w3.y, acc[n].y);
        }
    }
#pragma unroll
    for (int n = 0; n < 8; ++n) {
        const int node = node0 + nb + n;
        if (node < N_NODES) {
            const float ax = acc[n].x, ay = acc[n].y;
            const float sx = ax * fast_rcp(1.0f + __expf(-ax));
            const float sy = ay * fast_rcp(1.0f + __expf(-ay));
            hhf[(size_t)node * 64 + lane] = h22u(__floats2half2_rn(sx, sy));
        }
    }
}

// ---------------- edge-parallel gather-aggregate (packed-fp16 radial, fp16 h) --------------
// 256 threads = 4 independent waves; wave owns 64 contiguous CSR edges.
// Phase A: lane=edge -> d, 9 dup-half2 RBFs + row/col -> LDS [64][12] u32.
// Phase B: lane=channel pair; 8 groups of 8 edges, depth-2 pipelined fp16 h-gather;
// radial = silu_h2(rbf.wch + bch): 9 hfma2 + 7; msg = 1 hfma2 into half2 sub-acc,
// promoted to f32 at group ends and segment flushes (fp16 chain <= 8).
__global__ __launch_bounds__(256) void aggregate_kernel(
        const unsigned int* __restrict__ hhf, const float* __restrict__ pos,
        const int2* __restrict__ rc_csr,
        const float* __restrict__ Wc, const float* __restrict__ bc,
        float* __restrict__ agg) {
    __shared__ unsigned int rbf_s[4][WEDGES][12];   // 12 KB/block
    const int t = threadIdx.x;
    const int lane = t & 63;
    const int wv = t >> 6;
    const int base = (blockIdx.x * 4 + wv) * WEDGES;

    __half2 wch[D_COUNT];
#pragma unroll
    for (int k = 0; k < D_COUNT; ++k)
        wch[k] = __floats2half2_rn(Wc[k * C_H + 2 * lane], Wc[k * C_H + 2 * lane + 1]);
    const __half2 bch = __floats2half2_rn(bc[2 * lane], bc[2 * lane + 1]);
    const __half2 one2 = __floats2half2_rn(1.0f, 1.0f);
    const __half2 hzero = __floats2half2_rn(0.0f, 0.0f);

    // Phase A: one edge per lane
    {
        const int2 rc = rc_csr[base + lane];
        const float dx = pos[rc.x * 3 + 0] - pos[rc.y * 3 + 0];
        const float dy = pos[rc.x * 3 + 1] - pos[rc.y * 3 + 1];
        const float dz = pos[rc.x * 3 + 2] - pos[rc.y * 3 + 2];
        const float d = sqrtf(dx * dx + dy * dy + dz * dz);
#pragma unroll
        for (int k = 0; k < D_COUNT; ++k) {
            const float u = fmaf(d, 1.5f, -1.125f * (float)k);  // (d - 0.75k)*1.5
            const float r = __expf(-u * u);
            rbf_s[wv][lane][k] = h22u(__floats2half2_rn(r, r));
        }
        rbf_s[wv][lane][9]  = (unsigned int)rc.x;
        rbf_s[wv][lane][10] = (unsigned int)rc.y;
    }
    asm volatile("s_waitcnt lgkmcnt(0)" ::: "memory");
    __builtin_amdgcn_sched_barrier(0);
    __builtin_amdgcn_wave_barrier();

    unsigned int huA[8], huB[8];
    unsigned int r8A[8], r8B[8];
    int colA[8], colB[8];
    __half2 acc2 = hzero;
    float2 accf = make_float2(0.0f, 0.0f);
    int sCur;
    bool first = true;

#define LOADG(g, HU, R8, CO)                                                  \
    {                                                                         \
        _Pragma("unroll")                                                     \
        for (int u = 0; u < 8; ++u) {                                         \
            const uint4 m = *(const uint4*)&rbf_s[wv][(g) * 8 + u][8];        \
            const int sRow = __builtin_amdgcn_readfirstlane((int)m.y);        \
            CO[u] = __builtin_amdgcn_readfirstlane((int)m.z);                 \
            R8[u] = m.x;                                                      \
            HU[u] = hhf[(size_t)sRow * 64 + lane];                            \
        }                                                                     \
    }

#define COMPUTEG(g, HU, R8, CO)                                               \
    {                                                                         \
        _Pragma("unroll")                                                     \
        for (int u = 0; u < 8; ++u) {                                         \
            if (CO[u] != sCur) {                                              \
                const float2 pf = __half22float2(acc2);                       \
                accf.x += pf.x; accf.y += pf.y; acc2 = hzero;                 \
                float* dst = &agg[(size_t)sCur * C_H + 2 * lane];             \
                if (first) {                                                  \
                    atomicAdd(dst, accf.x); atomicAdd(dst + 1, accf.y);       \
                    first = false;                                            \
                } else {                                                      \
                    dst[0] = accf.x; dst[1] = accf.y;                         \
                }                                                             \
                accf.x = 0.0f; accf.y = 0.0f;                                 \
                sCur = CO[u];                                                 \
            }                                                                 \
            const uint4 q0 = *(const uint4*)&rbf_s[wv][(g) * 8 + u][0];       \
            const uint4 q1 = *(const uint4*)&rbf_s[wv][(g) * 8 + u][4];       \
            __half2 a = __hfma2(u2h2(q0.x), wch[0], bch);                     \
            a = __hfma2(u2h2(q0.y), wch[1], a);                               \
            a = __hfma2(u2h2(q0.z), wch[2], a);                               \
            a = __hfma2(u2h2(q0.w), wch[3], a);                               \
            a = __hfma2(u2h2(q1.x), wch[4], a);                               \
            a = __hfma2(u2h2(q1.y), wch[5], a);                               \
            a = __hfma2(u2h2(q1.z), wch[6], a);                               \
            a = __hfma2(u2h2(q1.w), wch[7], a);                               \
            a = __hfma2(u2h2(R8[u]), wch[8], a);                              \
            const __half2 ex = h2exp(__hneg2(a));                             \
            const __half2 sg = __hmul2(a, h2rcp(__hadd2(one2, ex)));          \
            acc2 = __hfma2(u2h2(HU[u]), sg, acc2);                            \
        }                                                                     \
        const float2 pg = __half22float2(acc2);                               \
        accf.x += pg.x; accf.y += pg.y; acc2 = hzero;                         \
    }

    LOADG(0, huA, r8A, colA);
    sCur = colA[0];
    LOADG(1, huB, r8B, colB);
    COMPUTEG(0, huA, r8A, colA);
    LOADG(2, huA, r8A, colA);
    COMPUTEG(1, huB, r8B, colB);
    LOADG(3, huB, r8B, colB);
    COMPUTEG(2, huA, r8A, colA);
    LOADG(4, huA, r8A, colA);
    COMPUTEG(3, huB, r8B, colB);
    LOADG(5, huB, r8B, colB);
    COMPUTEG(4, huA, r8A, colA);
    LOADG(6, huA, r8A, colA);
    COMPUTEG(5, huB, r8B, colB);
    LOADG(7, huB, r8B, colB);
    COMPUTEG(6, huA, r8A, colA);
    COMPUTEG(7, huB, r8B, colB);

    {
        float* dst = &agg[(size_t)sCur * C_H + 2 * lane];
        atomicAdd(dst, accf.x);
        atomicAdd(dst + 1, accf.y);
    }
#undef LOADG
#undef COMPUTEG
}

// ---------------- node: h' = g*lrelu((h+agg)@Wn + bn)/sqrt(1+eps)+be; POOL fuses add-pool --
// LDS stages (h+agg) as DUPLICATED half2 per (node,k); k-loop = hfma2 with f32 promotion
// every 32 k. POOL=1 (last layer): skip h-store, run-accumulate into out[batch[node]].
template <int POOL>
__global__ __launch_bounds__(256) void node_kernel(
        unsigned int* __restrict__ hhf, const float2* __restrict__ agg2,
        const unsigned int* __restrict__ Wnh, const float* __restrict__ bn,
        const float* __restrict__ g, const float* __restrict__ be,
        const int* __restrict__ batch, float* __restrict__ out) {
    __shared__ unsigned int s[32][C_H];   // dup half2 per (n,k): 16 KB
    const int node0 = blockIdx.x * 32;
    const int t = threadIdx.x;
    for (int i = t; i < 32 * 64; i += 256) {
        const int n = i >> 6;
        const int p = i & 63;
        if (node0 + n < N_NODES) {
            const float2 hv = __half22float2(u2h2(hhf[(size_t)(node0 + n) * 64 + p]));
            const float2 av = agg2[(size_t)(node0 + n) * 64 + p];
            const float vx = hv.x + av.x;
            const float vy = hv.y + av.y;
            s[n][2 * p]     = h22u(__floats2half2_rn(vx, vx));
            s[n][2 * p + 1] = h22u(__floats2half2_rn(vy, vy));
        }
    }
    __syncthreads();
    const int wv = t >> 6;
    const int lane = t & 63;
    const int nb = wv * 8;
    const float2 bn2 = *(const float2*)&bn[2 * lane];
    const __half2 hzero = __floats2half2_rn(0.0f, 0.0f);
    float2 accf[8];
    __half2 acc2[8];
#pragma unroll
    for (int n = 0; n < 8; ++n) { accf[n] = bn2; acc2[n] = hzero; }
    for (int kb = 0; kb < C_H; kb += 32) {
#pragma unroll
        for (int k4 = 0; k4 < 32; k4 += 4) {
            const int k = kb + k4;
            const unsigned int w0 = Wnh[(size_t)(k + 0) * 64 + lane];
            const unsigned int w1 = Wnh[(size_t)(k + 1) * 64 + lane];
            const unsigned int w2 = Wnh[(size_t)(k + 2) * 64 + lane];
            const unsigned int w3 = Wnh[(size_t)(k + 3) * 64 + lane];
#pragma unroll
            for (int n = 0; n < 8; ++n) {
                const uint4 sv = *(const uint4*)&s[nb + n][k];
                acc2[n] = __hfma2(u2h2(sv.x), u2h2(w0), acc2[n]);
                acc2[n] = __hfma2(u2h2(sv.y), u2h2(w1), acc2[n]);
                acc2[n] = __hfma2(u2h2(sv.z), u2h2(w2), acc2[n]);
                acc2[n] = __hfma2(u2h2(sv.w), u2h2(w3), acc2[n]);
            }
        }
#pragma unroll
        for (int n = 0; n < 8; ++n) {
            const float2 pf = __half22float2(acc2[n]);
            accf[n].x += pf.x; accf[n].y += pf.y;
            acc2[n] = hzero;
        }
    }
    const float inv = 0.9999950000374997f;  // 1/sqrt(1+1e-5)
    float2 g2 = *(const float2*)&g[2 * lane];
    g2.x *= inv; g2.y *= inv;
    const float2 be2 = *(const float2*)&be[2 * lane];
    if (POOL == 0) {
#pragma unroll
        for (int n = 0; n < 8; ++n) {
            const int node = node0 + nb + n;
            if (node < N_NODES) {
                float2 v = accf[n];
                v.x = v.x > 0.0f ? v.x : LRELU_SLOPE * v.x;
                v.y = v.y > 0.0f ? v.y : LRELU_SLOPE * v.y;
                const float ox = fmaf(g2.x, v.x, be2.x);
                const float oy = fmaf(g2.y, v.y, be2.y);
                hhf[(size_t)node * 64 + lane] = h22u(__floats2half2_rn(ox, oy));
            }
        }
    } else {
        // fused global_add_pool (batch sorted): run-accumulate over this wave's 8 nodes
        float2 pacc = make_float2(0.0f, 0.0f);
        int curb = -1;
#pragma unroll
        for (int n = 0; n < 8; ++n) {
            const int node = node0 + nb + n;
            if (node < N_NODES) {
                float2 v = accf[n];
                v.x = v.x > 0.0f ? v.x : LRELU_SLOPE * v.x;
                v.y = v.y > 0.0f ? v.y : LRELU_SLOPE * v.y;
                const float ox = fmaf(g2.x, v.x, be2.x);
                const float oy = fmaf(g2.y, v.y, be2.y);
                const int bb = batch[node];
                if (bb != curb) {
                    if (curb >= 0) {
                        atomicAdd(&out[curb * C_H + 2 * lane], pacc.x);
                        atomicAdd(&out[curb * C_H + 2 * lane + 1], pacc.y);
                    }
                    pacc = make_float2(0.0f, 0.0f);
                    curb = bb;
                }
                pacc.x += ox;
                pacc.y += oy;
            }
        }
        if (curb >= 0) {
            atomicAdd(&out[curb * C_H + 2 * lane], pacc.x);
            atomicAdd(&out[curb * C_H + 2 * lane + 1], pacc.y);
        }
    }
}

extern "C" void kernel_launch(void* const* d_in, const int* in_sizes, int n_in,
                              void* d_out, int out_size, void* d_ws, size_t ws_size,
                              hipStream_t stream) {
    const float* x     = (const float*)d_in[0];
    const float* pos   = (const float*)d_in[1];
    const int*   eidx  = (const int*)d_in[2];
    const int*   batch = (const int*)d_in[3];
    const float* W_lin = (const float*)d_in[4];
    const float* b_lin = (const float*)d_in[5];

    float* agg = (float*)d_ws;                                         // 6,400,000 f
    unsigned int* hhf = (unsigned int*)(agg + (size_t)N_NODES * C_H);  // 3,200,000 u32
    int* counts    = (int*)(hhf + (size_t)N_NODES * 64);               // 50,000
    int* curp      = counts + N_NODES;                                 // 50,000
    int* blocksums = curp + N_NODES;                                   // 256
    int2* rc_csr   = (int2*)(blocksums + 256);                         // 800,000 int2
    unsigned int* Wnh = (unsigned int*)(rc_csr + N_EDGES);             // 8192 u32

    const int* row = eidx;
    const int* col = eidx + N_EDGES;

    // CSR build
    hipMemsetAsync(counts, 0, N_NODES * sizeof(int), stream);
    hipLaunchKernelGGL(hist_kernel, dim3((N_EDGES + 255) / 256), dim3(256), 0, stream,
                       col, counts);
    hipLaunchKernelGGL(scan_a, dim3(SCAN_BLK), dim3(256), 0, stream,
                       counts, curp, blocksums);
    hipLaunchKernelGGL(scan_b, dim3(1), dim3(256), 0, stream, blocksums);
    hipLaunchKernelGGL(scan_c, dim3(SCAN_BLK), dim3(256), 0, stream, curp, blocksums);
    hipLaunchKernelGGL(scatter_kernel, dim3((N_EDGES + 255) / 256), dim3(256), 0, stream,
                       row, col, curp, rc_csr);

    hipLaunchKernelGGL(lin0_kernel, dim3((N_NODES + 31) / 32), dim3(256), 0, stream,
                       x, W_lin, b_lin, hhf);

    hipMemsetAsync(d_out, 0, (size_t)NUM_GRAPHS * C_H * sizeof(float), stream);

    for (int l = 0; l < 3; ++l) {
        const float* Wc = (const float*)d_in[6 + l * 6 + 0];
        const float* bc = (const float*)d_in[6 + l * 6 + 1];
        const float* Wn = (const float*)d_in[6 + l * 6 + 2];
        const float* bn = (const float*)d_in[6 + l * 6 + 3];
        const float* g  = (const float*)d_in[6 + l * 6 + 4];
        const float* be = (const float*)d_in[6 + l * 6 + 5];

        hipMemsetAsync(agg, 0, (size_t)N_NODES * C_H * sizeof(float), stream);
        hipLaunchKernelGGL(aggregate_kernel, dim3(NCHUNK / 4), dim3(256), 0, stream,
                           hhf, pos, rc_csr, Wc, bc, agg);
        hipLaunchKernelGGL(cvt_wn_kernel, dim3((C_H * 64 + 255) / 256), dim3(256), 0, stream,
                           Wn, Wnh);
        if (l < 2) {
            hipLaunchKernelGGL(HIP_KERNEL_NAME(node_kernel<0>),
                               dim3((N_NODES + 31) / 32), dim3(256), 0, stream,
                               hhf, (const float2*)agg, Wnh, bn, g, be, batch, (float*)d_out);
        } else {
            hipLaunchKernelGGL(HIP_KERNEL_NAME(node_kernel<1>),
                               dim3((N_NODES + 31) / 32), dim3(256), 0, stream,
                               hhf, (const float2*)agg, Wnh, bn, g, be, batch, (float*)d_out);
        }
    }
}

// Round 9
// 382.688 us; speedup vs baseline: 1.7482x; 1.0894x over previous
//
#include <hip/hip_runtime.h>
#include <hip/hip_fp16.h>
#include <math.h>

#define N_NODES 50000
#define N_EDGES 800000
#define NUM_GRAPHS 256
#define C_IN 64
#define C_H 128
#define D_COUNT 9
#define LRELU_SLOPE 0.01f
#define TAB_BINS 8192
#define TAB_SCALE 1024.0f                  // bins per unit distance, covers d in [0,8)
#define WEDGES 64                          // edges per wave
#define NCHUNK (N_EDGES / WEDGES)          // 12500 wave-chunks
#define SCAN_BLK ((N_NODES + 255) / 256)   // 196

__device__ __forceinline__ float fast_rcp(float x) { return __builtin_amdgcn_rcpf(x); }
__device__ __forceinline__ __half2 u2h2(unsigned int u) { return __builtin_bit_cast(__half2, u); }
__device__ __forceinline__ unsigned int h22u(__half2 h) { return __builtin_bit_cast(unsigned int, h); }

// ---------------- CSR build (once; edge structure shared by all 3 layers) ------------------

__global__ void hist_kernel(const int* __restrict__ col, int* __restrict__ counts) {
    const int e = blockIdx.x * 256 + threadIdx.x;
    if (e < N_EDGES) atomicAdd(&counts[col[e]], 1);
}

__global__ void scan_a(const int* __restrict__ counts, int* __restrict__ curp,
                       int* __restrict__ blocksums) {
    __shared__ int s[256];
    const int t = threadIdx.x;
    const int i = blockIdx.x * 256 + t;
    const int v = (i < N_NODES) ? counts[i] : 0;
    s[t] = v;
    __syncthreads();
    for (int d = 1; d < 256; d <<= 1) {
        const int x = (t >= d) ? s[t - d] : 0;
        __syncthreads();
        s[t] += x;
        __syncthreads();
    }
    if (i < N_NODES) curp[i] = s[t] - v;
    if (t == 255) blocksums[blockIdx.x] = s[255];
}

__global__ void scan_b(int* __restrict__ blocksums) {
    __shared__ int s[256];
    const int t = threadIdx.x;
    const int v = (t < SCAN_BLK) ? blocksums[t] : 0;
    s[t] = v;
    __syncthreads();
    for (int d = 1; d < 256; d <<= 1) {
        const int x = (t >= d) ? s[t - d] : 0;
        __syncthreads();
        s[t] += x;
        __syncthreads();
    }
    if (t < SCAN_BLK) blocksums[t] = s[t] - v;
}

__global__ void scan_c(int* __restrict__ curp, const int* __restrict__ blocksums) {
    const int i = blockIdx.x * 256 + threadIdx.x;
    if (i < N_NODES) curp[i] += blocksums[blockIdx.x];
}

// scatter into CSR order, precomputing the radial-table bin from d (layer-independent)
__global__ void scatter_kernel(const int* __restrict__ row, const int* __restrict__ col,
                               const float* __restrict__ pos,
                               int* __restrict__ cur, uint4* __restrict__ rcb_csr) {
    const int e = blockIdx.x * 256 + threadIdx.x;
    if (e < N_EDGES) {
        const int r = row[e];
        const int cl = col[e];
        const float dx = pos[r * 3 + 0] - pos[cl * 3 + 0];
        const float dy = pos[r * 3 + 1] - pos[cl * 3 + 1];
        const float dz = pos[r * 3 + 2] - pos[cl * 3 + 2];
        const float d = sqrtf(dx * dx + dy * dy + dz * dz);
        int bin = (int)(d * TAB_SCALE);
        bin = bin < TAB_BINS - 1 ? bin : TAB_BINS - 1;  // radial saturates for d>~8
        const int p = atomicAdd(&cur[cl], 1);
        rcb_csr[p] = make_uint4((unsigned int)r, (unsigned int)cl, (unsigned int)bin, 0u);
    }
}

// ---------------- per-layer radial table: tabh[bin][lane] = half2 radial(d_bin) ------------
__global__ void build_table_kernel(const float* __restrict__ Wc, const float* __restrict__ bc,
                                   unsigned int* __restrict__ tabh) {
    const int idx = blockIdx.x * 256 + threadIdx.x;
    if (idx >= TAB_BINS * 64) return;
    const int lane = idx & 63;
    const int bin = idx >> 6;
    const float d = ((float)bin + 0.5f) * (1.0f / TAB_SCALE);  // bin center (nearest)
    float v[2];
#pragma unroll
    for (int p = 0; p < 2; ++p) {
        const int c = 2 * lane + p;
        float a = bc[c];
#pragma unroll
        for (int k = 0; k < D_COUNT; ++k) {
            const float u = (d - 0.75f * (float)k) * 1.5f;  // mu=0.75k, 1/sigma=1.5
            a = fmaf(__expf(-u * u), Wc[k * C_H + c], a);
        }
        v[p] = a * fast_rcp(1.0f + __expf(-a));
    }
    tabh[idx] = h22u(__floats2half2_rn(v[0], v[1]));
}

// ---------------- hhf = half2(silu(x @ W_lin + b_lin)) -------------------------------------
__global__ __launch_bounds__(256) void lin0_kernel(
        const float* __restrict__ x, const float* __restrict__ W,
        const float* __restrict__ b, unsigned int* __restrict__ hhf) {
    __shared__ float xs[32][C_IN];
    const int node0 = blockIdx.x * 32;
    const int t = threadIdx.x;
    for (int i = t * 4; i < 32 * C_IN; i += 256 * 4) {
        const int n = i >> 6;
        const int c = i & 63;
        if (node0 + n < N_NODES)
            *(float4*)&xs[n][c] = *(const float4*)&x[(size_t)(node0 + n) * C_IN + c];
    }
    __syncthreads();
    const int wv = t >> 6;
    const int lane = t & 63;
    const int nb = wv * 8;
    const float2 b2 = *(const float2*)&b[2 * lane];
    float2 acc[8];
#pragma unroll
    for (int n = 0; n < 8; ++n) acc[n] = b2;
    for (int k = 0; k < C_IN; k += 4) {
        const float2 w0 = *(const float2*)&W[(size_t)(k + 0) * C_H + 2 * lane];
        const float2 w1 = *(const float2*)&W[(size_t)(k + 1) * C_H + 2 * lane];
        const float2 w2 = *(const float2*)&W[(size_t)(k + 2) * C_H + 2 * lane];
        const float2 w3 = *(const float2*)&W[(size_t)(k + 3) * C_H + 2 * lane];
#pragma unroll
        for (int n = 0; n < 8; ++n) {
            const float4 sv = *(const float4*)&xs[nb + n][k];
            acc[n].x = fmaf(sv.x, w0.x, acc[n].x); acc[n].y = fmaf(sv.x, w0.y, acc[n].y);
            acc[n].x = fmaf(sv.y, w1.x, acc[n].x); acc[n].y = fmaf(sv.y, w1.y, acc[n].y);
            acc[n].x = fmaf(sv.z, w2.x, acc[n].x); acc[n].y = fmaf(sv.z, w2.y, acc[n].y);
            acc[n].x = fmaf(sv.w, w3.x, acc[n].x); acc[n].y = fmaf(sv.w, w3.y, acc[n].y);
        }
    }
#pragma unroll
    for (int n = 0; n < 8; ++n) {
        const int node = node0 + nb + n;
        if (node < N_NODES) {
            const float ax = acc[n].x, ay = acc[n].y;
            const float sx = ax * fast_rcp(1.0f + __expf(-ax));
            const float sy = ay * fast_rcp(1.0f + __expf(-ay));
            hhf[(size_t)node * 64 + lane] = h22u(__floats2half2_rn(sx, sy));
        }
    }
}

// ---------------- edge-parallel gather-aggregate (table radial, fp16 h) --------------------
// 256 threads = 4 independent waves; wave owns 64 contiguous CSR edges.
// Phase A: lane=edge -> copy uint4(row,col,bin) to LDS. Phase B: lane=channel pair;
// 8 groups of 8 edges, depth-2 pipelined dual gathers (h dword + table dword);
// msg = 1 hfma2 into half2 sub-acc, promoted to f32 at group ends and flushes.
__global__ __launch_bounds__(256) void aggregate_kernel(
        const unsigned int* __restrict__ hhf, const uint4* __restrict__ rcb_csr,
        const unsigned int* __restrict__ tabh, float* __restrict__ agg) {
    __shared__ uint4 meta[4][WEDGES];   // 4 KB/block
    const int t = threadIdx.x;
    const int lane = t & 63;
    const int wv = t >> 6;
    const int base = (blockIdx.x * 4 + wv) * WEDGES;

    const __half2 hzero = __floats2half2_rn(0.0f, 0.0f);

    // Phase A: one edge per lane
    meta[wv][lane] = rcb_csr[base + lane];
    asm volatile("s_waitcnt lgkmcnt(0)" ::: "memory");
    __builtin_amdgcn_sched_barrier(0);
    __builtin_amdgcn_wave_barrier();

    unsigned int huA[8], huB[8];
    unsigned int tvA[8], tvB[8];
    int colA[8], colB[8];
    __half2 acc2 = hzero;
    float2 accf = make_float2(0.0f, 0.0f);
    int sCur;
    bool first = true;

#define LOADG(g, HU, TV, CO)                                                  \
    {                                                                         \
        _Pragma("unroll")                                                     \
        for (int u = 0; u < 8; ++u) {                                         \
            const uint4 m = meta[wv][(g) * 8 + u];                            \
            const int sRow = __builtin_amdgcn_readfirstlane((int)m.x);        \
            CO[u] = __builtin_amdgcn_readfirstlane((int)m.y);                 \
            const int sBin = __builtin_amdgcn_readfirstlane((int)m.z);        \
            HU[u] = hhf[(size_t)sRow * 64 + lane];                            \
            TV[u] = tabh[(size_t)sBin * 64 + lane];                           \
        }                                                                     \
    }

#define COMPUTEG(g, HU, TV, CO)                                               \
    {                                                                         \
        _Pragma("unroll")                                                     \
        for (int u = 0; u < 8; ++u) {                                         \
            if (CO[u] != sCur) {                                              \
                const float2 pf = __half22float2(acc2);                       \
                accf.x += pf.x; accf.y += pf.y; acc2 = hzero;                 \
                float* dst = &agg[(size_t)sCur * C_H + 2 * lane];             \
                if (first) {                                                  \
                    atomicAdd(dst, accf.x); atomicAdd(dst + 1, accf.y);       \
                    first = false;                                            \
                } else {                                                      \
                    dst[0] = accf.x; dst[1] = accf.y;                         \
                }                                                             \
                accf.x = 0.0f; accf.y = 0.0f;                                 \
                sCur = CO[u];                                                 \
            }                                                                 \
            acc2 = __hfma2(u2h2(HU[u]), u2h2(TV[u]), acc2);                   \
        }                                                                     \
        const float2 pg = __half22float2(acc2);                               \
        accf.x += pg.x; accf.y += pg.y; acc2 = hzero;                         \
    }

    LOADG(0, huA, tvA, colA);
    sCur = colA[0];
    LOADG(1, huB, tvB, colB);
    COMPUTEG(0, huA, tvA, colA);
    LOADG(2, huA, tvA, colA);
    COMPUTEG(1, huB, tvB, colB);
    LOADG(3, huB, tvB, colB);
    COMPUTEG(2, huA, tvA, colA);
    LOADG(4, huA, tvA, colA);
    COMPUTEG(3, huB, tvB, colB);
    LOADG(5, huB, tvB, colB);
    COMPUTEG(4, huA, tvA, colA);
    LOADG(6, huA, tvA, colA);
    COMPUTEG(5, huB, tvB, colB);
    LOADG(7, huB, tvB, colB);
    COMPUTEG(6, huA, tvA, colA);
    COMPUTEG(7, huB, tvB, colB);

    {
        float* dst = &agg[(size_t)sCur * C_H + 2 * lane];
        atomicAdd(dst, accf.x);
        atomicAdd(dst + 1, accf.y);
    }
#undef LOADG
#undef COMPUTEG
}

// ---------------- Wn -> half2 pairs ---------------------------------------------------------
__global__ void cvt_wn_kernel(const float* __restrict__ Wn, unsigned int* __restrict__ Wnh) {
    const int i = blockIdx.x * 256 + threadIdx.x;
    if (i < C_H * 64) {
        const int k = i >> 6, p = i & 63;
        Wnh[i] = h22u(__floats2half2_rn(Wn[k * C_H + 2 * p], Wn[k * C_H + 2 * p + 1]));
    }
}

// ---------------- node: h' = g*lrelu((h+agg)@Wn + bn)/sqrt(1+eps)+be; POOL fuses add-pool --
template <int POOL>
__global__ __launch_bounds__(256) void node_kernel(
        unsigned int* __restrict__ hhf, const float2* __restrict__ agg2,
        const unsigned int* __restrict__ Wnh, const float* __restrict__ bn,
        const float* __restrict__ g, const float* __restrict__ be,
        const int* __restrict__ batch, float* __restrict__ out) {
    __shared__ unsigned int s[32][C_H];   // dup half2 per (n,k): 16 KB
    const int node0 = blockIdx.x * 32;
    const int t = threadIdx.x;
    for (int i = t; i < 32 * 64; i += 256) {
        const int n = i >> 6;
        const int p = i & 63;
        if (node0 + n < N_NODES) {
            const float2 hv = __half22float2(u2h2(hhf[(size_t)(node0 + n) * 64 + p]));
            const float2 av = agg2[(size_t)(node0 + n) * 64 + p];
            const float vx = hv.x + av.x;
            const float vy = hv.y + av.y;
            s[n][2 * p]     = h22u(__floats2half2_rn(vx, vx));
            s[n][2 * p + 1] = h22u(__floats2half2_rn(vy, vy));
        }
    }
    __syncthreads();
    const int wv = t >> 6;
    const int lane = t & 63;
    const int nb = wv * 8;
    const float2 bn2 = *(const float2*)&bn[2 * lane];
    const __half2 hzero = __floats2half2_rn(0.0f, 0.0f);
    float2 accf[8];
    __half2 acc2[8];
#pragma unroll
    for (int n = 0; n < 8; ++n) { accf[n] = bn2; acc2[n] = hzero; }
    for (int kb = 0; kb < C_H; kb += 32) {
#pragma unroll
        for (int k4 = 0; k4 < 32; k4 += 4) {
            const int k = kb + k4;
            const unsigned int w0 = Wnh[(size_t)(k + 0) * 64 + lane];
            const unsigned int w1 = Wnh[(size_t)(k + 1) * 64 + lane];
            const unsigned int w2 = Wnh[(size_t)(k + 2) * 64 + lane];
            const unsigned int w3 = Wnh[(size_t)(k + 3) * 64 + lane];
#pragma unroll
            for (int n = 0; n < 8; ++n) {
                const uint4 sv = *(const uint4*)&s[nb + n][k];
                acc2[n] = __hfma2(u2h2(sv.x), u2h2(w0), acc2[n]);
                acc2[n] = __hfma2(u2h2(sv.y), u2h2(w1), acc2[n]);
                acc2[n] = __hfma2(u2h2(sv.z), u2h2(w2), acc2[n]);
                acc2[n] = __hfma2(u2h2(sv.w), u2h2(w3), acc2[n]);
            }
        }
#pragma unroll
        for (int n = 0; n < 8; ++n) {
            const float2 pf = __half22float2(acc2[n]);
            accf[n].x += pf.x; accf[n].y += pf.y;
            acc2[n] = hzero;
        }
    }
    const float inv = 0.9999950000374997f;  // 1/sqrt(1+1e-5)
    float2 g2 = *(const float2*)&g[2 * lane];
    g2.x *= inv; g2.y *= inv;
    const float2 be2 = *(const float2*)&be[2 * lane];
    if (POOL == 0) {
#pragma unroll
        for (int n = 0; n < 8; ++n) {
            const int node = node0 + nb + n;
            if (node < N_NODES) {
                float2 v = accf[n];
                v.x = v.x > 0.0f ? v.x : LRELU_SLOPE * v.x;
                v.y = v.y > 0.0f ? v.y : LRELU_SLOPE * v.y;
                const float ox = fmaf(g2.x, v.x, be2.x);
                const float oy = fmaf(g2.y, v.y, be2.y);
                hhf[(size_t)node * 64 + lane] = h22u(__floats2half2_rn(ox, oy));
            }
        }
    } else {
        float2 pacc = make_float2(0.0f, 0.0f);
        int curb = -1;
#pragma unroll
        for (int n = 0; n < 8; ++n) {
            const int node = node0 + nb + n;
            if (node < N_NODES) {
                float2 v = accf[n];
                v.x = v.x > 0.0f ? v.x : LRELU_SLOPE * v.x;
                v.y = v.y > 0.0f ? v.y : LRELU_SLOPE * v.y;
                const float ox = fmaf(g2.x, v.x, be2.x);
                const float oy = fmaf(g2.y, v.y, be2.y);
                const int bb = batch[node];
                if (bb != curb) {
                    if (curb >= 0) {
                        atomicAdd(&out[curb * C_H + 2 * lane], pacc.x);
                        atomicAdd(&out[curb * C_H + 2 * lane + 1], pacc.y);
                    }
                    pacc = make_float2(0.0f, 0.0f);
                    curb = bb;
                }
                pacc.x += ox;
                pacc.y += oy;
            }
        }
        if (curb >= 0) {
            atomicAdd(&out[curb * C_H + 2 * lane], pacc.x);
            atomicAdd(&out[curb * C_H + 2 * lane + 1], pacc.y);
        }
    }
}

extern "C" void kernel_launch(void* const* d_in, const int* in_sizes, int n_in,
                              void* d_out, int out_size, void* d_ws, size_t ws_size,
                              hipStream_t stream) {
    const float* x     = (const float*)d_in[0];
    const float* pos   = (const float*)d_in[1];
    const int*   eidx  = (const int*)d_in[2];
    const int*   batch = (const int*)d_in[3];
    const float* W_lin = (const float*)d_in[4];
    const float* b_lin = (const float*)d_in[5];

    float* agg = (float*)d_ws;                                         // 25.6 MB
    unsigned int* hhf = (unsigned int*)(agg + (size_t)N_NODES * C_H);  // 12.8 MB
    int* counts    = (int*)(hhf + (size_t)N_NODES * 64);               // 50,000
    int* curp      = counts + N_NODES;                                 // 50,000
    int* blocksums = curp + N_NODES;                                   // 256
    unsigned int* Wnh  = (unsigned int*)(blocksums + 256);             // 8192 u32
    unsigned int* tabh = Wnh + C_H * 64;                               // 2 MB
    // align rcb_csr to 16B
    uintptr_t p = (uintptr_t)(tabh + (size_t)TAB_BINS * 64);
    p = (p + 15) & ~(uintptr_t)15;
    uint4* rcb_csr = (uint4*)p;                                        // 12.8 MB

    const int* row = eidx;
    const int* col = eidx + N_EDGES;

    // CSR build (with per-edge table bin, layer-independent)
    hipMemsetAsync(counts, 0, N_NODES * sizeof(int), stream);
    hipLaunchKernelGGL(hist_kernel, dim3((N_EDGES + 255) / 256), dim3(256), 0, stream,
                       col, counts);
    hipLaunchKernelGGL(scan_a, dim3(SCAN_BLK), dim3(256), 0, stream,
                       counts, curp, blocksums);
    hipLaunchKernelGGL(scan_b, dim3(1), dim3(256), 0, stream, blocksums);
    hipLaunchKernelGGL(scan_c, dim3(SCAN_BLK), dim3(256), 0, stream, curp, blocksums);
    hipLaunchKernelGGL(scatter_kernel, dim3((N_EDGES + 255) / 256), dim3(256), 0, stream,
                       row, col, pos, curp, rcb_csr);

    hipLaunchKernelGGL(lin0_kernel, dim3((N_NODES + 31) / 32), dim3(256), 0, stream,
                       x, W_lin, b_lin, hhf);

    hipMemsetAsync(d_out, 0, (size_t)NUM_GRAPHS * C_H * sizeof(float), stream);

    for (int l = 0; l < 3; ++l) {
        const float* Wc = (const float*)d_in[6 + l * 6 + 0];
        const float* bc = (const float*)d_in[6 + l * 6 + 1];
        const float* Wn = (const float*)d_in[6 + l * 6 + 2];
        const float* bn = (const float*)d_in[6 + l * 6 + 3];
        const float* g  = (const float*)d_in[6 + l * 6 + 4];
        const float* be = (const float*)d_in[6 + l * 6 + 5];

        hipLaunchKernelGGL(build_table_kernel, dim3(TAB_BINS * 64 / 256), dim3(256), 0, stream,
                           Wc, bc, tabh);
        hipMemsetAsync(agg, 0, (size_t)N_NODES * C_H * sizeof(float), stream);
        hipLaunchKernelGGL(aggregate_kernel, dim3(NCHUNK / 4), dim3(256), 0, stream,
                           hhf, rcb_csr, tabh, agg);
        hipLaunchKernelGGL(cvt_wn_kernel, dim3((C_H * 64 + 255) / 256), dim3(256), 0, stream,
                           Wn, Wnh);
        if (l < 2) {
            hipLaunchKernelGGL(HIP_KERNEL_NAME(node_kernel<0>),
                               dim3((N_NODES + 31) / 32), dim3(256), 0, stream,
                               hhf, (const float2*)agg, Wnh, bn, g, be, batch, (float*)d_out);
        } else {
            hipLaunchKernelGGL(HIP_KERNEL_NAME(node_kernel<1>),
                               dim3((N_NODES + 31) / 32), dim3(256), 0, stream,
                               hhf, (const float2*)agg, Wnh, bn, g, be, batch, (float*)d_out);
        }
    }
}

// Round 10
// 320.330 us; speedup vs baseline: 2.0885x; 1.1947x over previous
//
#include <hip/hip_runtime.h>
#include <hip/hip_fp16.h>
#include <math.h>

#define N_NODES 50000
#define N_EDGES 800000
#define NUM_GRAPHS 256
#define C_IN 64
#define C_H 128
#define D_COUNT 9
#define LRELU_SLOPE 0.01f
#define TAB_BINS 8192
#define TAB_SCALE 1024.0f                  // bins per unit distance, covers d in [0,8)
#define WEDGES 64                          // edges per wave
#define NCHUNK (N_EDGES / WEDGES)          // 12500 wave-chunks
#define NBUCK ((N_NODES + 255) / 256)      // 196 coarse buckets (col>>8)
#define REGION_CAP 6144                    // per-bucket region capacity (mean 4081, +32 sigma)
#define SCAT_BLK_EDGES 2048

__device__ __forceinline__ float fast_rcp(float x) { return __builtin_amdgcn_rcpf(x); }
__device__ __forceinline__ __half2 u2h2(unsigned int u) { return __builtin_bit_cast(__half2, u); }
__device__ __forceinline__ unsigned int h22u(__half2 h) { return __builtin_bit_cast(unsigned int, h); }

// ---------------- bucketed CSR build (once; edge structure shared by all 3 layers) ---------
// Pass 1: privatized scatter into fixed per-bucket regions (bucket = col>>8), computing the
// radial-table bin from d on the way. Records are 8B: uint2(row | col<<16, bin).
__global__ __launch_bounds__(256) void bscatter_kernel(
        const int* __restrict__ row, const int* __restrict__ col,
        const float* __restrict__ pos, int* __restrict__ bcur, uint2* __restrict__ ebuf) {
    __shared__ int lhist[NBUCK];
    __shared__ int lcur[NBUCK];
    const int t = threadIdx.x;
    const int e0 = blockIdx.x * SCAT_BLK_EDGES;
    for (int i = t; i < NBUCK; i += 256) lhist[i] = 0;
    __syncthreads();

    int myb[8];
    uint2 myrec[8];
#pragma unroll
    for (int s = 0; s < 8; ++s) {
        const int e = e0 + s * 256 + t;
        if (e < N_EDGES) {
            const int r = row[e];
            const int c = col[e];
            const float dx = pos[r * 3 + 0] - pos[c * 3 + 0];
            const float dy = pos[r * 3 + 1] - pos[c * 3 + 1];
            const float dz = pos[r * 3 + 2] - pos[c * 3 + 2];
            const float d = sqrtf(dx * dx + dy * dy + dz * dz);
            int bin = (int)(d * TAB_SCALE);
            bin = bin < TAB_BINS - 1 ? bin : TAB_BINS - 1;  // radial saturates beyond table
            myb[s] = c >> 8;
            myrec[s] = make_uint2((unsigned int)r | ((unsigned int)c << 16),
                                  (unsigned int)bin);
            atomicAdd(&lhist[myb[s]], 1);
        } else {
            myb[s] = -1;
        }
    }
    __syncthreads();
    for (int i = t; i < NBUCK; i += 256)
        lcur[i] = (lhist[i] > 0) ? atomicAdd(&bcur[i], lhist[i]) : 0;
    __syncthreads();
#pragma unroll
    for (int s = 0; s < 8; ++s) {
        if (myb[s] >= 0) {
            const int p = atomicAdd(&lcur[myb[s]], 1);
            ebuf[(size_t)myb[s] * REGION_CAP + p] = myrec[s];
        }
    }
}

// Pass 2: exclusive scan of bucket counts -> bofs[NBUCK+1]
__global__ void bscan_kernel(const int* __restrict__ bcur, int* __restrict__ bofs) {
    __shared__ int s[256];
    const int t = threadIdx.x;
    const int v = (t < NBUCK) ? bcur[t] : 0;
    s[t] = v;
    __syncthreads();
    for (int d = 1; d < 256; d <<= 1) {
        const int x = (t >= d) ? s[t - d] : 0;
        __syncthreads();
        s[t] += x;
        __syncthreads();
    }
    if (t < NBUCK) bofs[t] = s[t] - v;
    if (t == 0) bofs[NBUCK] = N_EDGES;
}

// Pass 3: per-bucket LDS counting sort by col&255 -> compact col-sorted CSR (coalesced-ish)
__global__ __launch_bounds__(256) void bsort_kernel(
        const uint2* __restrict__ ebuf, const int* __restrict__ bcur,
        const int* __restrict__ bofs, uint2* __restrict__ rcb) {
    __shared__ uint2 se[REGION_CAP];   // 48 KB
    __shared__ int lhist[256];
    __shared__ int lcur[256];
    const int b = blockIdx.x;
    const int t = threadIdx.x;
    const int n = bcur[b];
    const uint2* src = ebuf + (size_t)b * REGION_CAP;
    for (int i = t; i < n; i += 256) se[i] = src[i];
    lhist[t] = 0;
    __syncthreads();
    for (int i = t; i < n; i += 256)
        atomicAdd(&lhist[(se[i].x >> 16) & 255u], 1);
    __syncthreads();
    // exclusive scan of lhist
    int v = lhist[t];
    int sv = v;
    lcur[t] = v;
    __syncthreads();
    for (int d = 1; d < 256; d <<= 1) {
        const int x = (t >= d) ? lcur[t - d] : 0;
        __syncthreads();
        lcur[t] += x;
        __syncthreads();
        sv = lcur[t];
    }
    __syncthreads();
    lcur[t] = sv - v;  // exclusive
    __syncthreads();
    const int dbase = bofs[b];
    for (int i = t; i < n; i += 256) {
        const uint2 e = se[i];
        const int dst = atomicAdd(&lcur[(e.x >> 16) & 255u], 1);
        rcb[dbase + dst] = e;
    }
}

// ---------------- per-layer radial table: tabh[bin][lane] = half2 radial(d_bin) ------------
__global__ void build_table_kernel(const float* __restrict__ Wc, const float* __restrict__ bc,
                                   unsigned int* __restrict__ tabh) {
    const int idx = blockIdx.x * 256 + threadIdx.x;
    if (idx >= TAB_BINS * 64) return;
    const int lane = idx & 63;
    const int bin = idx >> 6;
    const float d = ((float)bin + 0.5f) * (1.0f / TAB_SCALE);  // bin center (nearest)
    float v[2];
#pragma unroll
    for (int p = 0; p < 2; ++p) {
        const int c = 2 * lane + p;
        float a = bc[c];
#pragma unroll
        for (int k = 0; k < D_COUNT; ++k) {
            const float u = (d - 0.75f * (float)k) * 1.5f;  // mu=0.75k, 1/sigma=1.5
            a = fmaf(__expf(-u * u), Wc[k * C_H + c], a);
        }
        v[p] = a * fast_rcp(1.0f + __expf(-a));
    }
    tabh[idx] = h22u(__floats2half2_rn(v[0], v[1]));
}

// ---------------- hhf = half2(silu(x @ W_lin + b_lin)) -------------------------------------
__global__ __launch_bounds__(256) void lin0_kernel(
        const float* __restrict__ x, const float* __restrict__ W,
        const float* __restrict__ b, unsigned int* __restrict__ hhf) {
    __shared__ float xs[32][C_IN];
    const int node0 = blockIdx.x * 32;
    const int t = threadIdx.x;
    for (int i = t * 4; i < 32 * C_IN; i += 256 * 4) {
        const int n = i >> 6;
        const int c = i & 63;
        if (node0 + n < N_NODES)
            *(float4*)&xs[n][c] = *(const float4*)&x[(size_t)(node0 + n) * C_IN + c];
    }
    __syncthreads();
    const int wv = t >> 6;
    const int lane = t & 63;
    const int nb = wv * 8;
    const float2 b2 = *(const float2*)&b[2 * lane];
    float2 acc[8];
#pragma unroll
    for (int n = 0; n < 8; ++n) acc[n] = b2;
    for (int k = 0; k < C_IN; k += 4) {
        const float2 w0 = *(const float2*)&W[(size_t)(k + 0) * C_H + 2 * lane];
        const float2 w1 = *(const float2*)&W[(size_t)(k + 1) * C_H + 2 * lane];
        const float2 w2 = *(const float2*)&W[(size_t)(k + 2) * C_H + 2 * lane];
        const float2 w3 = *(const float2*)&W[(size_t)(k + 3) * C_H + 2 * lane];
#pragma unroll
        for (int n = 0; n < 8; ++n) {
            const float4 sv = *(const float4*)&xs[nb + n][k];
            acc[n].x = fmaf(sv.x, w0.x, acc[n].x); acc[n].y = fmaf(sv.x, w0.y, acc[n].y);
            acc[n].x = fmaf(sv.y, w1.x, acc[n].x); acc[n].y = fmaf(sv.y, w1.y, acc[n].y);
            acc[n].x = fmaf(sv.z, w2.x, acc[n].x); acc[n].y = fmaf(sv.z, w2.y, acc[n].y);
            acc[n].x = fmaf(sv.w, w3.x, acc[n].x); acc[n].y = fmaf(sv.w, w3.y, acc[n].y);
        }
    }
#pragma unroll
    for (int n = 0; n < 8; ++n) {
        const int node = node0 + nb + n;
        if (node < N_NODES) {
            const float ax = acc[n].x, ay = acc[n].y;
            const float sx = ax * fast_rcp(1.0f + __expf(-ax));
            const float sy = ay * fast_rcp(1.0f + __expf(-ay));
            hhf[(size_t)node * 64 + lane] = h22u(__floats2half2_rn(sx, sy));
        }
    }
}

// ---------------- edge-parallel gather-aggregate (table radial, fp16 h) --------------------
__global__ __launch_bounds__(256) void aggregate_kernel(
        const unsigned int* __restrict__ hhf, const uint2* __restrict__ rcb,
        const unsigned int* __restrict__ tabh, float* __restrict__ agg) {
    __shared__ uint2 meta[4][WEDGES];   // 2 KB/block
    const int t = threadIdx.x;
    const int lane = t & 63;
    const int wv = t >> 6;
    const int base = (blockIdx.x * 4 + wv) * WEDGES;

    const __half2 hzero = __floats2half2_rn(0.0f, 0.0f);

    meta[wv][lane] = rcb[base + lane];
    asm volatile("s_waitcnt lgkmcnt(0)" ::: "memory");
    __builtin_amdgcn_sched_barrier(0);
    __builtin_amdgcn_wave_barrier();

    unsigned int huA[8], huB[8];
    unsigned int tvA[8], tvB[8];
    int colA[8], colB[8];
    __half2 acc2 = hzero;
    float2 accf = make_float2(0.0f, 0.0f);
    int sCur;
    bool first = true;

#define LOADG(g, HU, TV, CO)                                                  \
    {                                                                         \
        _Pragma("unroll")                                                     \
        for (int u = 0; u < 8; ++u) {                                         \
            const uint2 m = meta[wv][(g) * 8 + u];                            \
            const unsigned int rcu = __builtin_amdgcn_readfirstlane(m.x);     \
            const int sBin = __builtin_amdgcn_readfirstlane((int)m.y);        \
            const int sRow = (int)(rcu & 0xffffu);                            \
            CO[u] = (int)(rcu >> 16);                                         \
            HU[u] = hhf[(size_t)sRow * 64 + lane];                            \
            TV[u] = tabh[(size_t)sBin * 64 + lane];                           \
        }                                                                     \
    }

#define COMPUTEG(g, HU, TV, CO)                                               \
    {                                                                         \
        _Pragma("unroll")                                                     \
        for (int u = 0; u < 8; ++u) {                                         \
            if (CO[u] != sCur) {                                              \
                const float2 pf = __half22float2(acc2);                       \
                accf.x += pf.x; accf.y += pf.y; acc2 = hzero;                 \
                float* dst = &agg[(size_t)sCur * C_H + 2 * lane];             \
                if (first) {                                                  \
                    atomicAdd(dst, accf.x); atomicAdd(dst + 1, accf.y);       \
                    first = false;                                            \
                } else {                                                      \
                    dst[0] = accf.x; dst[1] = accf.y;                         \
                }                                                             \
                accf.x = 0.0f; accf.y = 0.0f;                                 \
                sCur = CO[u];                                                 \
            }                                                                 \
            acc2 = __hfma2(u2h2(HU[u]), u2h2(TV[u]), acc2);                   \
        }                                                                     \
        const float2 pg = __half22float2(acc2);                               \
        accf.x += pg.x; accf.y += pg.y; acc2 = hzero;                         \
    }

    LOADG(0, huA, tvA, colA);
    sCur = colA[0];
    LOADG(1, huB, tvB, colB);
    COMPUTEG(0, huA, tvA, colA);
    LOADG(2, huA, tvA, colA);
    COMPUTEG(1, huB, tvB, colB);
    LOADG(3, huB, tvB, colB);
    COMPUTEG(2, huA, tvA, colA);
    LOADG(4, huA, tvA, colA);
    COMPUTEG(3, huB, tvB, colB);
    LOADG(5, huB, tvB, colB);
    COMPUTEG(4, huA, tvA, colA);
    LOADG(6, huA, tvA, colA);
    COMPUTEG(5, huB, tvB, colB);
    LOADG(7, huB, tvB, colB);
    COMPUTEG(6, huA, tvA, colA);
    COMPUTEG(7, huB, tvB, colB);

    {
        float* dst = &agg[(size_t)sCur * C_H + 2 * lane];
        atomicAdd(dst, accf.x);
        atomicAdd(dst + 1, accf.y);
    }
#undef LOADG
#undef COMPUTEG
}

// ---------------- Wn -> half2 pairs ---------------------------------------------------------
__global__ void cvt_wn_kernel(const float* __restrict__ Wn, unsigned int* __restrict__ Wnh) {
    const int i = blockIdx.x * 256 + threadIdx.x;
    if (i < C_H * 64) {
        const int k = i >> 6, p = i & 63;
        Wnh[i] = h22u(__floats2half2_rn(Wn[k * C_H + 2 * p], Wn[k * C_H + 2 * p + 1]));
    }
}

// ---------------- node: h' = g*lrelu((h+agg)@Wn + bn)/sqrt(1+eps)+be; POOL fuses add-pool --
template <int POOL>
__global__ __launch_bounds__(256) void node_kernel(
        unsigned int* __restrict__ hhf, const float2* __restrict__ agg2,
        const unsigned int* __restrict__ Wnh, const float* __restrict__ bn,
        const float* __restrict__ g, const float* __restrict__ be,
        const int* __restrict__ batch, float* __restrict__ out) {
    __shared__ unsigned int s[32][C_H];   // dup half2 per (n,k): 16 KB
    const int node0 = blockIdx.x * 32;
    const int t = threadIdx.x;
    for (int i = t; i < 32 * 64; i += 256) {
        const int n = i >> 6;
        const int p = i & 63;
        if (node0 + n < N_NODES) {
            const float2 hv = __half22float2(u2h2(hhf[(size_t)(node0 + n) * 64 + p]));
            const float2 av = agg2[(size_t)(node0 + n) * 64 + p];
            const float vx = hv.x + av.x;
            const float vy = hv.y + av.y;
            s[n][2 * p]     = h22u(__floats2half2_rn(vx, vx));
            s[n][2 * p + 1] = h22u(__floats2half2_rn(vy, vy));
        }
    }
    __syncthreads();
    const int wv = t >> 6;
    const int lane = t & 63;
    const int nb = wv * 8;
    const float2 bn2 = *(const float2*)&bn[2 * lane];
    const __half2 hzero = __floats2half2_rn(0.0f, 0.0f);
    float2 accf[8];
    __half2 acc2[8];
#pragma unroll
    for (int n = 0; n < 8; ++n) { accf[n] = bn2; acc2[n] = hzero; }
    for (int kb = 0; kb < C_H; kb += 32) {
#pragma unroll
        for (int k4 = 0; k4 < 32; k4 += 4) {
            const int k = kb + k4;
            const unsigned int w0 = Wnh[(size_t)(k + 0) * 64 + lane];
            const unsigned int w1 = Wnh[(size_t)(k + 1) * 64 + lane];
            const unsigned int w2 = Wnh[(size_t)(k + 2) * 64 + lane];
            const unsigned int w3 = Wnh[(size_t)(k + 3) * 64 + lane];
#pragma unroll
            for (int n = 0; n < 8; ++n) {
                const uint4 sv = *(const uint4*)&s[nb + n][k];
                acc2[n] = __hfma2(u2h2(sv.x), u2h2(w0), acc2[n]);
                acc2[n] = __hfma2(u2h2(sv.y), u2h2(w1), acc2[n]);
                acc2[n] = __hfma2(u2h2(sv.z), u2h2(w2), acc2[n]);
                acc2[n] = __hfma2(u2h2(sv.w), u2h2(w3), acc2[n]);
            }
        }
#pragma unroll
        for (int n = 0; n < 8; ++n) {
            const float2 pf = __half22float2(acc2[n]);
            accf[n].x += pf.x; accf[n].y += pf.y;
            acc2[n] = hzero;
        }
    }
    const float inv = 0.9999950000374997f;  // 1/sqrt(1+1e-5)
    float2 g2 = *(const float2*)&g[2 * lane];
    g2.x *= inv; g2.y *= inv;
    const float2 be2 = *(const float2*)&be[2 * lane];
    if (POOL == 0) {
#pragma unroll
        for (int n = 0; n < 8; ++n) {
            const int node = node0 + nb + n;
            if (node < N_NODES) {
                float2 v = accf[n];
                v.x = v.x > 0.0f ? v.x : LRELU_SLOPE * v.x;
                v.y = v.y > 0.0f ? v.y : LRELU_SLOPE * v.y;
                const float ox = fmaf(g2.x, v.x, be2.x);
                const float oy = fmaf(g2.y, v.y, be2.y);
                hhf[(size_t)node * 64 + lane] = h22u(__floats2half2_rn(ox, oy));
            }
        }
    } else {
        float2 pacc = make_float2(0.0f, 0.0f);
        int curb = -1;
#pragma unroll
        for (int n = 0; n < 8; ++n) {
            const int node = node0 + nb + n;
            if (node < N_NODES) {
                float2 v = accf[n];
                v.x = v.x > 0.0f ? v.x : LRELU_SLOPE * v.x;
                v.y = v.y > 0.0f ? v.y : LRELU_SLOPE * v.y;
                const float ox = fmaf(g2.x, v.x, be2.x);
                const float oy = fmaf(g2.y, v.y, be2.y);
                const int bb = batch[node];
                if (bb != curb) {
                    if (curb >= 0) {
                        atomicAdd(&out[curb * C_H + 2 * lane], pacc.x);
                        atomicAdd(&out[curb * C_H + 2 * lane + 1], pacc.y);
                    }
                    pacc = make_float2(0.0f, 0.0f);
                    curb = bb;
                }
                pacc.x += ox;
                pacc.y += oy;
            }
        }
        if (curb >= 0) {
            atomicAdd(&out[curb * C_H + 2 * lane], pacc.x);
            atomicAdd(&out[curb * C_H + 2 * lane + 1], pacc.y);
        }
    }
}

extern "C" void kernel_launch(void* const* d_in, const int* in_sizes, int n_in,
                              void* d_out, int out_size, void* d_ws, size_t ws_size,
                              hipStream_t stream) {
    const float* x     = (const float*)d_in[0];
    const float* pos   = (const float*)d_in[1];
    const int*   eidx  = (const int*)d_in[2];
    const int*   batch = (const int*)d_in[3];
    const float* W_lin = (const float*)d_in[4];
    const float* b_lin = (const float*)d_in[5];

    float* agg = (float*)d_ws;                                         // 25.6 MB
    unsigned int* hhf = (unsigned int*)(agg + (size_t)N_NODES * C_H);  // 12.8 MB
    unsigned int* Wnh  = hhf + (size_t)N_NODES * 64;                   // 32 KB
    unsigned int* tabh = Wnh + C_H * 64;                               // 2 MB
    int* bcur = (int*)(tabh + (size_t)TAB_BINS * 64);                  // 196
    int* bofs = bcur + NBUCK;                                          // 197
    uintptr_t p = (uintptr_t)(bofs + NBUCK + 1);
    p = (p + 15) & ~(uintptr_t)15;
    uint2* ebuf = (uint2*)p;                                           // 196*6144*8 = 9.6 MB
    uint2* rcb  = ebuf + (size_t)NBUCK * REGION_CAP;                   // 6.4 MB

    const int* row = eidx;
    const int* col = eidx + N_EDGES;

    // bucketed CSR build (with per-edge table bin, layer-independent)
    hipMemsetAsync(bcur, 0, NBUCK * sizeof(int), stream);
    hipLaunchKernelGGL(bscatter_kernel,
                       dim3((N_EDGES + SCAT_BLK_EDGES - 1) / SCAT_BLK_EDGES), dim3(256),
                       0, stream, row, col, pos, bcur, ebuf);
    hipLaunchKernelGGL(bscan_kernel, dim3(1), dim3(256), 0, stream, bcur, bofs);
    hipLaunchKernelGGL(bsort_kernel, dim3(NBUCK), dim3(256), 0, stream,
                       ebuf, bcur, bofs, rcb);

    hipLaunchKernelGGL(lin0_kernel, dim3((N_NODES + 31) / 32), dim3(256), 0, stream,
                       x, W_lin, b_lin, hhf);

    hipMemsetAsync(d_out, 0, (size_t)NUM_GRAPHS * C_H * sizeof(float), stream);

    for (int l = 0; l < 3; ++l) {
        const float* Wc = (const float*)d_in[6 + l * 6 + 0];
        const float* bc = (const float*)d_in[6 + l * 6 + 1];
        const float* Wn = (const float*)d_in[6 + l * 6 + 2];
        const float* bn = (const float*)d_in[6 + l * 6 + 3];
        const float* g  = (const float*)d_in[6 + l * 6 + 4];
        const float* be = (const float*)d_in[6 + l * 6 + 5];

        hipLaunchKernelGGL(build_table_kernel, dim3(TAB_BINS * 64 / 256), dim3(256), 0, stream,
                           Wc, bc, tabh);
        hipMemsetAsync(agg, 0, (size_t)N_NODES * C_H * sizeof(float), stream);
        hipLaunchKernelGGL(aggregate_kernel, dim3(NCHUNK / 4), dim3(256), 0, stream,
                           hhf, rcb, tabh, agg);
        hipLaunchKernelGGL(cvt_wn_kernel, dim3((C_H * 64 + 255) / 256), dim3(256), 0, stream,
                           Wn, Wnh);
        if (l < 2) {
            hipLaunchKernelGGL(HIP_KERNEL_NAME(node_kernel<0>),
                               dim3((N_NODES + 31) / 32), dim3(256), 0, stream,
                               hhf, (const float2*)agg, Wnh, bn, g, be, batch, (float*)d_out);
        } else {
            hipLaunchKernelGGL(HIP_KERNEL_NAME(node_kernel<1>),
                               dim3((N_NODES + 31) / 32), dim3(256), 0, stream,
                               hhf, (const float2*)agg, Wnh, bn, g, be, batch, (float*)d_out);
        }
    }
}